// Round 2
// 1246.996 us; speedup vs baseline: 1.1149x; 1.1149x over previous
//
#include <hip/hip_runtime.h>

#define DEVINL __device__ __forceinline__

typedef short bf16x8 __attribute__((ext_vector_type(8)));
typedef float f32x4 __attribute__((ext_vector_type(4)));

DEVINL unsigned f2b(float f) {  // f32 -> bf16 bits (round to nearest even)
  unsigned u = __float_as_uint(f);
  u = (u + 0x7FFFu + ((u >> 16) & 1u)) >> 16;
  return u & 0xFFFFu;
}
DEVINL uint4 pack8(const float* v) {
  uint4 u;
  u.x = f2b(v[0]) | (f2b(v[1]) << 16);
  u.y = f2b(v[2]) | (f2b(v[3]) << 16);
  u.z = f2b(v[4]) | (f2b(v[5]) << 16);
  u.w = f2b(v[6]) | (f2b(v[7]) << 16);
  return u;
}

// ---------------- reduction helpers ----------------
DEVINL float4 block_sum4(float4 v, float4* sh) {
  const int lane = threadIdx.x & 63, wid = threadIdx.x >> 6;
#pragma unroll
  for (int o = 32; o; o >>= 1) {
    v.x += __shfl_down(v.x, o);
    v.y += __shfl_down(v.y, o);
    v.z += __shfl_down(v.z, o);
    v.w += __shfl_down(v.w, o);
  }
  __syncthreads();
  if (lane == 0) sh[wid] = v;
  __syncthreads();
  float4 a = sh[0], b = sh[1], c = sh[2], d = sh[3], r;
  r.x = a.x + b.x + c.x + d.x;
  r.y = a.y + b.y + c.y + d.y;
  r.z = a.z + b.z + c.z + d.z;
  r.w = a.w + b.w + c.w + d.w;
  return r;
}
DEVINL float block_sum1(float v, float* sh) {
  const int lane = threadIdx.x & 63, wid = threadIdx.x >> 6;
#pragma unroll
  for (int o = 32; o; o >>= 1) v += __shfl_down(v, o);
  __syncthreads();
  if (lane == 0) sh[wid] = v;
  __syncthreads();
  return sh[0] + sh[1] + sh[2] + sh[3];
}

// ---- table projection: P[v,j] = scl*(V[v,:] @ W[:,j]), P[nvec,j] = scl*(bias @ W) ----
__global__ __launch_bounds__(256) void tabproj_kernel(
    const float* __restrict__ V, const float* __restrict__ bias,
    const float* __restrict__ W, float* __restrict__ P, int nvec, float scl) {
  __shared__ float4 sh4[4];
  const int j = blockIdx.x, tid = threadIdx.x;
  float acc[4] = {0.f, 0.f, 0.f, 0.f};
  for (int kk = tid; kk < 512; kk += 256) {
    const float w = W[(size_t)kk * 512 + j];
    for (int v = 0; v < nvec; ++v) acc[v] += V[(size_t)v * 512 + kk] * w;
    acc[3] += bias[kk] * w;
  }
  float4 packed = make_float4(acc[0], acc[1], acc[2], acc[3]);
  packed = block_sum4(packed, sh4);
  if (tid == 0) {
    const float vals[4] = {packed.x * scl, packed.y * scl, packed.z * scl, packed.w * scl};
    for (int v = 0; v < nvec; ++v) P[(size_t)v * 512 + j] = vals[v];
    P[(size_t)nvec * 512 + j] = vals[3];
  }
}

// ---- weight prep: src f32 [K][N] -> dst bf16 [N][K], scaled ----
__global__ __launch_bounds__(256) void transpose_bf_kernel(
    const float* __restrict__ src, unsigned short* __restrict__ dst, int K, int N,
    float scl) {
  __shared__ float tile[32][33];
  const int n0 = blockIdx.x * 32, k0 = blockIdx.y * 32;
  const int tx = threadIdx.x, ty = threadIdx.y;  // 32 x 8
#pragma unroll
  for (int r = 0; r < 4; ++r)
    tile[ty + 8 * r][tx] = src[(size_t)(k0 + ty + 8 * r) * N + n0 + tx];
  __syncthreads();
#pragma unroll
  for (int r = 0; r < 4; ++r)
    dst[(size_t)(n0 + ty + 8 * r) * K + k0 + tx] =
        (unsigned short)f2b(scl * tile[tx][ty + 8 * r]);
}

// ---- pack self-side K (frag layout) + Q (packed bf16) from KVQ f32 [4096][1536] ----
// Kfr: [bh][kc=D/32][stile=64][lane=64][8]; Qbf: [bh][s][D].  nh=2, D=256.
__global__ __launch_bounds__(128) void pack_kq_kernel(
    const float* __restrict__ KVQ, unsigned short* __restrict__ Kfr,
    unsigned short* __restrict__ Qbf) {
  const int row = blockIdx.x;  // b*1024 + s
  const int b = row >> 10, s = row & 1023;
  const int t = threadIdx.x;
  const bool isQ = t >= 64;
  const int c = t & 63;
  const int h = c >> 5;           // 32 chunks of 8 per head
  const int d0 = (c & 31) * 8;
  const float* src = KVQ + (size_t)row * 1536 + (isQ ? 1024 : 0) + h * 256 + d0;
  float v[8];
  *(float4*)v = *(const float4*)src;
  *(float4*)(v + 4) = *(const float4*)(src + 4);
  const uint4 u = pack8(v);
  const int bh = b * 2 + h;
  if (isQ) {
    *(uint4*)(Qbf + ((size_t)bh * 1024 + s) * 256 + d0) = u;
  } else {
    const int kc = d0 >> 5;
    const int lane = ((d0 & 31) >> 3) * 16 + (s & 15);
    *(uint4*)(Kfr + ((size_t)(bh * 8 + kc) * 64 + (s >> 4)) * 512 + lane * 8) = u;
  }
}

// ---- V f32 [4096][ld] (head cols at h*D) -> Vfr [bh][sc=32][dtile=D/16][lane][8] ----
__global__ __launch_bounds__(256) void vtrans_frag_kernel(
    const float* __restrict__ V, int ld, int nh, int D,
    unsigned short* __restrict__ Vfr) {
  __shared__ float tile[32][33];
  const int s0 = blockIdx.x * 32, d0 = blockIdx.y * 32;
  const int bh = blockIdx.z;
  const int b = bh / nh, h = bh % nh;
  const int tx = threadIdx.x, ty = threadIdx.y;  // 32 x 8
  const float* src = V + ((size_t)b * 1024 + s0) * ld + h * D + d0;
#pragma unroll
  for (int r = 0; r < 4; ++r)
    tile[ty + 8 * r][tx] = src[(size_t)(ty + 8 * r) * ld + tx];  // [s][d]
  __syncthreads();
  const int idx = ty * 32 + tx;
  if (idx < 128) {
    const int dj = idx & 31, sch = idx >> 5;  // d within tile, s-chunk of 8
    float v[8];
#pragma unroll
    for (int jj = 0; jj < 8; ++jj) v[jj] = tile[sch * 8 + jj][dj];
    const uint4 u = pack8(v);
    const int sc = s0 >> 5;
    const int dtile = (d0 + dj) >> 4;
    const int lane = sch * 16 + (dj & 15);
    *(uint4*)(Vfr + ((size_t)(bh * 32 + sc) * (D / 16) + dtile) * 512 + lane * 8) = u;
  }
}

// ---- cross-side encoder: rank-3 affine -> Kfr + Qbf (packed) + V f32 ----
// nh=2, D=256. Tables T*: rows 0..2 = vectors, row 3 (at +1536) = bias.
__global__ __launch_bounds__(256) void affine3_pack_kernel(
    const float* __restrict__ cx, const float* __restrict__ cy, int sel,
    const float* __restrict__ TK, const float* __restrict__ TV,
    const float* __restrict__ TQ, unsigned short* __restrict__ Kfr,
    unsigned short* __restrict__ Qbf, float* __restrict__ Vf) {
  const int row = blockIdx.x;
  const int b = row >> 10, s = row & 1023;
  const float x = cx[row];
  const float* y = cy + (size_t)row * 8 + 2 * sel;
  const float y0 = y[0], y1 = y[1];
  const int t = threadIdx.x;
  if (t < 128) {
    const bool isQ = t >= 64;
    const int c = t & 63;
    const int h = c >> 5;
    const int d0 = (c & 31) * 8;
    const float* T = isQ ? TQ : TK;
    float v[8];
#pragma unroll
    for (int j = 0; j < 8; ++j) {
      const int col = h * 256 + d0 + j;
      v[j] = x * T[col] + y0 * T[512 + col] + y1 * T[1024 + col] + T[1536 + col];
    }
    const uint4 u = pack8(v);
    const int bh = b * 2 + h;
    if (isQ) {
      *(uint4*)(Qbf + ((size_t)bh * 1024 + s) * 256 + d0) = u;
    } else {
      const int kc = d0 >> 5;
      const int lane = ((d0 & 31) >> 3) * 16 + (s & 15);
      *(uint4*)(Kfr + ((size_t)(bh * 8 + kc) * 64 + (s >> 4)) * 512 + lane * 8) = u;
    }
  } else {
    const int col0 = (t - 128) * 4;
    float4 o;
    float* op = (float*)&o;
#pragma unroll
    for (int j = 0; j < 4; ++j) {
      const int col = col0 + j;
      op[j] = x * TV[col] + y0 * TV[512 + col] + y1 * TV[1024 + col] + TV[1536 + col];
    }
    *(float4*)(Vf + (size_t)row * 512 + col0) = o;
  }
}

// ---- decoder rank-1 producers (nh=4, D=128): T rows [0]=w, [1]=bias ----
__global__ __launch_bounds__(64) void rank1_pack_kernel(
    const float* __restrict__ x, const float* __restrict__ T,
    unsigned short* __restrict__ dst, int isQ) {
  const int row = blockIdx.x;
  const int b = row >> 10, s = row & 1023;
  const float xv = x[row];
  const int c = threadIdx.x;        // 64 chunks of 8
  const int h = c >> 4;             // 16 chunks per head
  const int d0 = (c & 15) * 8;
  float v[8];
#pragma unroll
  for (int j = 0; j < 8; ++j) {
    const int col = h * 128 + d0 + j;
    v[j] = xv * T[col] + T[512 + col];
  }
  const uint4 u = pack8(v);
  const int bh = b * 4 + h;
  if (isQ) {
    *(uint4*)(dst + ((size_t)bh * 1024 + s) * 128 + d0) = u;
  } else {
    const int kc = d0 >> 5;
    const int lane = ((d0 & 31) >> 3) * 16 + (s & 15);
    *(uint4*)(dst + ((size_t)(bh * 4 + kc) * 64 + (s >> 4)) * 512 + lane * 8) = u;
  }
}

// ---- f32 [4096][512] -> Qbf packed (nh=4, D=128), scaled ----
__global__ __launch_bounds__(64) void qpack_kernel(
    const float* __restrict__ Q, unsigned short* __restrict__ Qbf, float scl) {
  const int row = blockIdx.x;
  const int b = row >> 10, s = row & 1023;
  const int c = threadIdx.x;
  const int h = c >> 4;
  const int d0 = (c & 15) * 8;
  float v[8];
  const float* src = Q + (size_t)row * 512 + h * 128 + d0;
  *(float4*)v = *(const float4*)src;
  *(float4*)(v + 4) = *(const float4*)(src + 4);
#pragma unroll
  for (int j = 0; j < 8; ++j) v[j] *= scl;
  *(uint4*)(Qbf + ((size_t)(b * 4 + h) * 1024 + s) * 128 + d0) = pack8(v);
}

// ---- out[r,:] = cx[r]*W3[0,:] + y0*W3[1,:] + y1*W3[2,:] + bias (f32 + bf16) ----
__global__ __launch_bounds__(512) void affine3_kernel(
    const float* __restrict__ cx, const float* __restrict__ cy, int sel,
    const float* __restrict__ W3, const float* __restrict__ bias,
    float* __restrict__ out, unsigned short* __restrict__ outb) {
  const int r = blockIdx.x, j = threadIdx.x;
  const float* y = cy + (size_t)r * 8 + 2 * sel;
  const float v = cx[r] * W3[j] + y[0] * W3[512 + j] + y[1] * W3[1024 + j] + bias[j];
  if (out) out[(size_t)r * 512 + j] = v;
  if (outb) outb[(size_t)r * 512 + j] = (unsigned short)f2b(v);
}

// ---- out[r,:] = x[r]*w + b ----
__global__ __launch_bounds__(512) void rank1_kernel(
    const float* __restrict__ x, const float* __restrict__ w,
    const float* __restrict__ b, float* __restrict__ out,
    unsigned short* __restrict__ outb) {
  const int r = blockIdx.x, j = threadIdx.x;
  const float v = x[r] * w[j] + b[j];
  if (out) out[(size_t)r * 512 + j] = v;
  if (outb) outb[(size_t)r * 512 + j] = (unsigned short)f2b(v);
}

// ---------------- MFMA GEMM: C = [A0 | A1] @ Wt^T (+bias), bf16 in, f32 out ------
__global__ __launch_bounds__(256) void gemm_mfma_kernel(
    const unsigned short* __restrict__ A0, int K0,
    const unsigned short* __restrict__ A1, int K1,
    const unsigned short* __restrict__ Wt, const float* __restrict__ bias,
    float* __restrict__ C, int M, int N) {
  constexpr int BM = 128, BN = 64, BK = 32, LDP = 40;
  __shared__ unsigned short As[BM * LDP];
  __shared__ unsigned short Bs[BN * LDP];
  const int tid = threadIdx.x;
  const int lane = tid & 63, w = tid >> 6;
  const int bm = blockIdx.y * BM, bn = blockIdx.x * BN;
  const int wm = (w & 1) * 64, wn = (w >> 1) * 32;
  const int l15 = lane & 15, lq = lane >> 4;
  const int ar = tid >> 1, ac = (tid & 1) * 16;
  const int br = tid >> 2, bc = (tid & 3) * 8;
  const int Ktot = K0 + K1;
  f32x4 acc[4][2] = {};
  for (int k0 = 0; k0 < Ktot; k0 += BK) {
    const unsigned short* A;
    int kk, Ak;
    if (k0 < K0) { A = A0; kk = k0;      Ak = K0; }
    else         { A = A1; kk = k0 - K0; Ak = K1; }
    const uint4 a0 = *(const uint4*)(A + (size_t)(bm + ar) * Ak + kk + ac);
    const uint4 a1 = *(const uint4*)(A + (size_t)(bm + ar) * Ak + kk + ac + 8);
    const uint4 b0 = *(const uint4*)(Wt + (size_t)(bn + br) * Ktot + k0 + bc);
    __syncthreads();
    *(uint4*)(As + ar * LDP + ac) = a0;
    *(uint4*)(As + ar * LDP + ac + 8) = a1;
    *(uint4*)(Bs + br * LDP + bc) = b0;
    __syncthreads();
    bf16x8 af[4], bfr[2];
#pragma unroll
    for (int mt = 0; mt < 4; ++mt)
      af[mt] = *(const bf16x8*)(As + (wm + mt * 16 + l15) * LDP + lq * 8);
#pragma unroll
    for (int nt = 0; nt < 2; ++nt)
      bfr[nt] = *(const bf16x8*)(Bs + (wn + nt * 16 + l15) * LDP + lq * 8);
#pragma unroll
    for (int mt = 0; mt < 4; ++mt)
#pragma unroll
      for (int nt = 0; nt < 2; ++nt)
        acc[mt][nt] =
            __builtin_amdgcn_mfma_f32_16x16x32_bf16(af[mt], bfr[nt], acc[mt][nt], 0, 0, 0);
  }
#pragma unroll
  for (int nt = 0; nt < 2; ++nt) {
    const int col = bn + wn + nt * 16 + l15;
    const float bv = bias ? bias[col] : 0.f;
#pragma unroll
    for (int mt = 0; mt < 4; ++mt) {
#pragma unroll
      for (int r = 0; r < 4; ++r) {
        const int row = bm + wm + mt * 16 + lq * 4 + r;
        C[(size_t)row * N + col] = acc[mt][nt][r] + bv;
      }
    }
  }
}

// ---------------- MFMA flash attention, frag-packed inputs -----------------------
// Block = 16 q rows of one (b,head) vs ONE KV side; 4 waves own 256 keys each.
// Q pre-scaled.  No max-subtraction: LN-normalized inputs keep |score| ~ O(2),
// so exp() is exact softmax (identical up to fp rounding) -- removes the max
// reduction + 2 barriers and the QK^T->exp cross-wave serialization.
// NKV==2: grid = 2*512, side = blockIdx>>9; writes f32 partials to Rp (the two
// sides are independent complete softmaxes); a separate addcvt kernel sums them.
// NKV==1: writes bf16 directly with post_scale.
// Qbf: [bh][s][D] bf16. Kfr: [bh][kc][stile][lane][8]. Vfr: [bh][sc][dtile][lane][8].
template <int D, int NKV>
__global__ __launch_bounds__(256, 2) void attn_mfma_kernel(
    const unsigned short* __restrict__ Qa, const unsigned short* __restrict__ Qb,
    const unsigned short* __restrict__ KfrA, const unsigned short* __restrict__ KfrB,
    const unsigned short* __restrict__ VfrA, const unsigned short* __restrict__ VfrB,
    float post_scale, int nh, unsigned short* __restrict__ R,
    float* __restrict__ Rp) {
  constexpr int NQS = NKV;
  constexpr int QP = D + 8;
  constexpr int WP = 1024 + 8;
  constexpr int DT = D / 64;
  const int tid = threadIdx.x;
  const int lane = tid & 63, w = tid >> 6;
  const int l15 = lane & 15, lq = lane >> 4;
  const int nbh = 4 * nh;
  int bx = blockIdx.x;
  int side = 0;
  if constexpr (NKV == 2) { side = bx >> 9; bx &= 511; }
  const int bh = bx % nbh;                   // XCD-local (b,h)
  const int qb16 = (bx / nbh) * 16;
  const int b = bh / nh, head = bh % nh;
  const size_t rowb = (size_t)b * 1024;
  const int colo = head * D;

  __shared__ unsigned short qsh[NQS * 16 * QP];
  __shared__ unsigned short wsh[16 * WP];
  __shared__ float redA[4][16];
  __shared__ float redB[4][16];

  // ---- stage Q tiles (vectorized bf16 copies) ----
  for (int idx = tid; idx < NQS * 16 * (D / 8); idx += 256) {
    const int st = idx / (16 * (D / 8));
    const int rem = idx - st * 16 * (D / 8);
    const int r = rem / (D / 8), ch = rem - r * (D / 8);
    const unsigned short* Q = st ? Qb : Qa;
    const uint4 u = *(const uint4*)(Q + ((size_t)bh * 1024 + qb16 + r) * D + ch * 8);
    *(uint4*)(qsh + st * 16 * QP + r * QP + ch * 8) = u;
  }
  __syncthreads();

  const unsigned short* Kp = (side ? KfrB : KfrA) + (size_t)bh * ((size_t)D * 1024);
  const unsigned short* Vp = (side ? VfrB : VfrA) + (size_t)bh * ((size_t)D * 1024);

  // ---- QK^T: batched kf loads, scores in C-layout regs ----
  f32x4 acc[NQS][16] = {};
#pragma unroll 1
  for (int kc = 0; kc < D / 32; ++kc) {
    bf16x8 kf[16];
#pragma unroll
    for (int st = 0; st < 16; ++st)
      kf[st] = *(const bf16x8*)(Kp + ((size_t)kc * 64 + w * 16 + st) * 512 + lane * 8);
    const bf16x8 qa = *(const bf16x8*)(qsh + l15 * QP + kc * 32 + lq * 8);
    __builtin_amdgcn_s_setprio(1);
#pragma unroll
    for (int st = 0; st < 16; ++st)
      acc[0][st] = __builtin_amdgcn_mfma_f32_16x16x32_bf16(qa, kf[st], acc[0][st], 0, 0, 0);
    __builtin_amdgcn_s_setprio(0);
    if constexpr (NQS == 2) {
      const bf16x8 qb2 = *(const bf16x8*)(qsh + 16 * QP + l15 * QP + kc * 32 + lq * 8);
      __builtin_amdgcn_s_setprio(1);
#pragma unroll
      for (int st = 0; st < 16; ++st)
        acc[1][st] =
            __builtin_amdgcn_mfma_f32_16x16x32_bf16(qb2, kf[st], acc[1][st], 0, 0, 0);
      __builtin_amdgcn_s_setprio(0);
    }
  }

  // ---- exp (no max shift) + row sum ----
  float psA[4] = {0.f, 0.f, 0.f, 0.f}, psB[4] = {0.f, 0.f, 0.f, 0.f};
#pragma unroll
  for (int st = 0; st < 16; ++st)
#pragma unroll
    for (int r = 0; r < 4; ++r) {
      acc[0][st][r] = __expf(acc[0][st][r]);
      psA[r] += acc[0][st][r];
      if constexpr (NQS == 2) {
        acc[1][st][r] = __expf(acc[1][st][r]);
        psB[r] += acc[1][st][r];
      }
    }
#pragma unroll
  for (int o = 1; o < 16; o <<= 1)
#pragma unroll
    for (int r = 0; r < 4; ++r) {
      psA[r] += __shfl_xor(psA[r], o);
      if constexpr (NQS == 2) psB[r] += __shfl_xor(psB[r], o);
    }
  if (l15 == 0) {
#pragma unroll
    for (int r = 0; r < 4; ++r) {
      redA[w][lq * 4 + r] = psA[r];
      if constexpr (NQS == 2) redB[w][lq * 4 + r] = psB[r];
    }
  }
  __syncthreads();
  float invA[4], invB[4];
#pragma unroll
  for (int r = 0; r < 4; ++r) {
    invA[r] = 1.f / (redA[0][lq * 4 + r] + redA[1][lq * 4 + r] +
                     redA[2][lq * 4 + r] + redA[3][lq * 4 + r]);
    if constexpr (NQS == 2)
      invB[r] = 1.f / (redB[0][lq * 4 + r] + redB[1][lq * 4 + r] +
                       redB[2][lq * 4 + r] + redB[3][lq * 4 + r]);
  }
  // ---- combined weight strip (bf16, A-operand layout) ----
#pragma unroll
  for (int st = 0; st < 16; ++st)
#pragma unroll
    for (int r = 0; r < 4; ++r) {
      float wv = acc[0][st][r] * invA[r];
      if constexpr (NQS == 2) wv += acc[1][st][r] * invB[r];
      wsh[(lq * 4 + r) * WP + w * 256 + st * 16 + l15] = (unsigned short)f2b(wv);
    }
  __syncthreads();

  // ---- PV: out[q][d] += W[q][s] V[s][d]; batch 2 sc-chunks of loads ----
  f32x4 acc_o[DT] = {};
#pragma unroll 1
  for (int sc = 0; sc < 32; sc += 2) {
    bf16x8 pa[2], vb[2][DT];
#pragma unroll
    for (int u = 0; u < 2; ++u) {
      pa[u] = *(const bf16x8*)(wsh + l15 * WP + (sc + u) * 32 + lq * 8);
#pragma unroll
      for (int dt = 0; dt < DT; ++dt)
        vb[u][dt] = *(const bf16x8*)(
            Vp + ((size_t)(sc + u) * (D / 16) + w * DT + dt) * 512 + lane * 8);
    }
    __builtin_amdgcn_s_setprio(1);
#pragma unroll
    for (int u = 0; u < 2; ++u)
#pragma unroll
      for (int dt = 0; dt < DT; ++dt)
        acc_o[dt] =
            __builtin_amdgcn_mfma_f32_16x16x32_bf16(pa[u], vb[u][dt], acc_o[dt], 0, 0, 0);
    __builtin_amdgcn_s_setprio(0);
  }

  // ---- epilogue: C layout row=lq*4+r -> q, col=l15 -> d ----
  if constexpr (NKV == 2) {
    float* dst = Rp + (size_t)side * (4096 * 512) + (rowb + qb16) * 512 + colo;
#pragma unroll
    for (int dt = 0; dt < DT; ++dt)
#pragma unroll
      for (int r = 0; r < 4; ++r) {
        const int q = lq * 4 + r;
        const int d = w * (DT * 16) + dt * 16 + l15;
        dst[(size_t)q * 512 + d] = acc_o[dt][r];
      }
  } else {
#pragma unroll
    for (int dt = 0; dt < DT; ++dt)
#pragma unroll
      for (int r = 0; r < 4; ++r) {
        const int q = lq * 4 + r;
        const int d = w * (DT * 16) + dt * 16 + l15;
        R[(rowb + qb16 + q) * 512 + colo + d] =
            (unsigned short)f2b(acc_o[dt][r] * post_scale);
      }
  }
}

// ---- combine side partials: O = bf16(A + B), 8 elems/thread ----
__global__ __launch_bounds__(256) void addcvt_kernel(
    const float* __restrict__ A, const float* __restrict__ B,
    unsigned short* __restrict__ O) {
  const size_t i = ((size_t)blockIdx.x * 256 + threadIdx.x) * 8;
  float v[8];
  *(float4*)v = *(const float4*)(A + i);
  *(float4*)(v + 4) = *(const float4*)(A + i + 4);
  const float4 b0 = *(const float4*)(B + i);
  const float4 b1 = *(const float4*)(B + i + 4);
  v[0] += b0.x; v[1] += b0.y; v[2] += b0.z; v[3] += b0.w;
  v[4] += b1.x; v[5] += b1.y; v[6] += b1.z; v[7] += b1.w;
  *(uint4*)(O + i) = pack8(v);
}

// ------------- out = LayerNorm(G + res) * g + b  (f32 out + optional bf16 out) ----
__global__ __launch_bounds__(256) void ln_kernel(
    const float* __restrict__ G, const float* __restrict__ res,
    const float* __restrict__ g, const float* __restrict__ b,
    float* __restrict__ out, unsigned short* __restrict__ outb) {
  __shared__ float sh[4];
  const int row = blockIdx.x, tid = threadIdx.x;
  const size_t off = (size_t)row * 512;
  const float x0 = G[off + tid] + res[off + tid];
  const float x1 = G[off + tid + 256] + res[off + tid + 256];
  const float mean = block_sum1(x0 + x1, sh) * (1.0f / 512.0f);
  const float d0 = x0 - mean, d1 = x1 - mean;
  const float var = block_sum1(d0 * d0 + d1 * d1, sh) * (1.0f / 512.0f);
  const float inv = rsqrtf(var + 1e-5f);
  const float y0 = d0 * inv * g[tid] + b[tid];
  const float y1 = d1 * inv * g[tid + 256] + b[tid + 256];
  out[off + tid] = y0;
  out[off + tid + 256] = y1;
  if (outb) {
    outb[off + tid] = (unsigned short)f2b(y0);
    outb[off + tid + 256] = (unsigned short)f2b(y1);
  }
}

extern "C" void kernel_launch(void* const* d_in, const int* in_sizes, int n_in,
                              void* d_out, int out_size, void* d_ws, size_t ws_size,
                              hipStream_t stream) {
  typedef unsigned short ushort_t;
  const float* cx   = (const float*)d_in[0];
  const float* cy   = (const float*)d_in[1];
  const float* txp  = (const float*)d_in[2];
  const float* in_W = (const float*)d_in[3];
  const float* in_b = (const float*)d_in[4];
  const float* cx_W = (const float*)d_in[5];
  const float* cx_b = (const float*)d_in[6];
  const float* tx_W = (const float*)d_in[7];
  const float* tx_b = (const float*)d_in[8];
  const float* sWk  = (const float*)d_in[9];
  const float* sWv  = (const float*)d_in[10];
  const float* sWq  = (const float*)d_in[11];
  const float* sWf  = (const float*)d_in[12];
  const float* sbf  = (const float*)d_in[13];
  const float* sg   = (const float*)d_in[14];
  const float* sb   = (const float*)d_in[15];
  const float* aWk  = (const float*)d_in[16];
  const float* aWv  = (const float*)d_in[17];
  const float* aWq  = (const float*)d_in[18];
  const float* aWf  = (const float*)d_in[19];
  const float* abf  = (const float*)d_in[20];
  const float* ag   = (const float*)d_in[21];
  const float* ab   = (const float*)d_in[22];

  const float SSC = 0.0625f;               // 1/sqrt(256)
  const float CSC = 0.08838834764831845f;  // 1/sqrt(128)

  const size_t MB = 1024 * 1024;
  char* ws = (char*)d_ws;
  float*    E     = (float*)(ws + 0 * MB);       // 8 MB
  ushort_t* Ebf   = (ushort_t*)(ws + 8 * MB);    // 4 MB
  float*    QA    = (float*)(ws + 12 * MB);      // 8 MB
  ushort_t* QAbf  = (ushort_t*)(ws + 20 * MB);   // 4 MB
  ushort_t* Rbbf  = (ushort_t*)(ws + 24 * MB);   // 4 MB
  float*    KVQ   = (float*)(ws + 28 * MB);      // 24 MB [4096][1536] K|V|Q
  float*    G     = KVQ;                          // alias: KVQ dead before Wf GEMM
  float*    Rp    = KVQ;                          // alias: attn f32 partials (2x8MB),
                                                  //   KVQ consumed by pack kernels first
  ushort_t* KfrA  = (ushort_t*)(ws + 52 * MB);   // 4 MB
  ushort_t* VfrA  = (ushort_t*)(ws + 56 * MB);   // 4 MB
  ushort_t* QbfA  = (ushort_t*)(ws + 60 * MB);   // 4 MB
  ushort_t* KfrB  = (ushort_t*)(ws + 64 * MB);   // 4 MB
  ushort_t* VfrB  = (ushort_t*)(ws + 68 * MB);   // 4 MB
  ushort_t* QbfB  = (ushort_t*)(ws + 72 * MB);   // 4 MB
  float*    cVf   = (float*)(ws + 76 * MB);      // 8 MB cross/decoder V f32
  float*    cQf   = (float*)(ws + 84 * MB);      // 8 MB decoder Q f32
  ushort_t* Wkvqt[2] = {(ushort_t*)(ws + 92 * MB),
                        (ushort_t*)(ws + 92 * MB + 1536 * 1024)};
  ushort_t* Wft[2]   = {(ushort_t*)(ws + 95 * MB), (ushort_t*)(ws + 96 * MB)};
  ushort_t* aWvt[2]  = {(ushort_t*)(ws + 97 * MB),
                        (ushort_t*)(ws + 97 * MB + 512 * 1024)};
  ushort_t* aWqt1    = (ushort_t*)(ws + 98 * MB);
  ushort_t* aWft[2]  = {(ushort_t*)(ws + 99 * MB), (ushort_t*)(ws + 100 * MB)};
  float*    Ttab     = (float*)(ws + 101 * MB);

  float* T_sc[2][3];
  for (int i = 0; i < 2; ++i)
    for (int w = 0; w < 3; ++w) T_sc[i][w] = Ttab + (size_t)(i * 3 + w) * 2048;
  float* T_cak[2] = {Ttab + 12288, Ttab + 12288 + 1024};
  float* T_caq0 = Ttab + 14336;

  const dim3 tb(32, 8);
  const dim3 tg512(16, 16), tg1024(16, 32);

  // ---- prep: weight transposes + projection tables (Q weights pre-scaled) ----
  for (int i = 0; i < 2; ++i) {
    transpose_bf_kernel<<<tg512, tb, 0, stream>>>(sWk + (size_t)i * 262144, Wkvqt[i], 512, 512, 1.f);
    transpose_bf_kernel<<<tg512, tb, 0, stream>>>(sWv + (size_t)i * 262144, Wkvqt[i] + 512 * 512, 512, 512, 1.f);
    transpose_bf_kernel<<<tg512, tb, 0, stream>>>(sWq + (size_t)i * 262144, Wkvqt[i] + 1024 * 512, 512, 512, SSC);
    transpose_bf_kernel<<<tg1024, tb, 0, stream>>>(sWf + (size_t)i * 524288, Wft[i], 1024, 512, 1.f);
    transpose_bf_kernel<<<tg512, tb, 0, stream>>>(aWv + (size_t)i * 262144, aWvt[i], 512, 512, 1.f);
    transpose_bf_kernel<<<tg1024, tb, 0, stream>>>(aWf + (size_t)i * 524288, aWft[i], 1024, 512, 1.f);
    tabproj_kernel<<<512, 256, 0, stream>>>(in_W, in_b, sWk + (size_t)i * 262144, T_sc[i][0], 3, 1.f);
    tabproj_kernel<<<512, 256, 0, stream>>>(in_W, in_b, sWv + (size_t)i * 262144, T_sc[i][1], 3, 1.f);
    tabproj_kernel<<<512, 256, 0, stream>>>(in_W, in_b, sWq + (size_t)i * 262144, T_sc[i][2], 3, SSC);
    tabproj_kernel<<<512, 256, 0, stream>>>(cx_W, cx_b, aWk + (size_t)i * 262144, T_cak[i], 1, 1.f);
  }
  transpose_bf_kernel<<<tg512, tb, 0, stream>>>(aWq + 262144, aWqt1, 512, 512, 1.f);
  tabproj_kernel<<<512, 256, 0, stream>>>(tx_W, tx_b, aWq, T_caq0, 1, CSC);

  // ---- initial activations ----
  affine3_kernel<<<4096, 512, 0, stream>>>(cx, cy, 0, in_W, in_b, E, Ebf);
  rank1_kernel<<<4096, 512, 0, stream>>>(txp, tx_W, tx_b, QA, QAbf);

  // ---- 8 self/cross encoder layers ----
  for (int p = 0; p < 4; ++p) {
    for (int i = 0; i < 2; ++i) {
      gemm_mfma_kernel<<<dim3(24, 32), 256, 0, stream>>>(Ebf, 512, nullptr, 0, Wkvqt[i],
                                                         nullptr, KVQ, 4096, 1536);
      pack_kq_kernel<<<4096, 128, 0, stream>>>(KVQ, KfrA, QbfA);
      vtrans_frag_kernel<<<dim3(32, 8, 8), tb, 0, stream>>>(KVQ + 512, 1536, 2, 256, VfrA);
      if (p > 0) {
        affine3_pack_kernel<<<4096, 256, 0, stream>>>(cx, cy, p, T_sc[i][0], T_sc[i][1],
                                                      T_sc[i][2], KfrB, QbfB, cVf);
        vtrans_frag_kernel<<<dim3(32, 8, 8), tb, 0, stream>>>(cVf, 512, 2, 256, VfrB);
        attn_mfma_kernel<256, 2><<<1024, 256, 0, stream>>>(
            QbfA, QbfB, KfrA, KfrB, VfrA, VfrB, 1.0f, 2, nullptr, Rp);
        addcvt_kernel<<<1024, 256, 0, stream>>>(Rp, Rp + 4096 * 512, Rbbf);
      } else {
        // x2 is x: 4 identical sdpa terms -> 4 * sdpa(sQ,sK,sV)
        attn_mfma_kernel<256, 1><<<512, 256, 0, stream>>>(
            QbfA, QbfA, KfrA, KfrA, VfrA, VfrA, 4.0f, 2, Rbbf, nullptr);
      }
      gemm_mfma_kernel<<<dim3(8, 32), 256, 0, stream>>>(Ebf, 512, Rbbf, 512, Wft[i],
                                                        sbf + (size_t)i * 512, G, 4096, 512);
      ln_kernel<<<4096, 256, 0, stream>>>(G, E, sg + (size_t)i * 512, sb + (size_t)i * 512,
                                          E, Ebf);
    }
  }

  // ---- 2 cross-attention decoder layers (nh=4, D=128) ----
  for (int i = 0; i < 2; ++i) {
    rank1_pack_kernel<<<4096, 64, 0, stream>>>(cx, T_cak[i], KfrA, 0);
    gemm_mfma_kernel<<<dim3(8, 32), 256, 0, stream>>>(Ebf, 512, nullptr, 0, aWvt[i],
                                                      nullptr, cVf, 4096, 512);
    vtrans_frag_kernel<<<dim3(32, 4, 16), tb, 0, stream>>>(cVf, 512, 4, 128, VfrA);
    if (i == 0) {
      rank1_pack_kernel<<<4096, 64, 0, stream>>>(txp, T_caq0, QbfB, 1);
    } else {
      gemm_mfma_kernel<<<dim3(8, 32), 256, 0, stream>>>(QAbf, 512, nullptr, 0, aWqt1,
                                                        nullptr, cQf, 4096, 512);
      qpack_kernel<<<4096, 64, 0, stream>>>(cQf, QbfB, CSC);
    }
    attn_mfma_kernel<128, 1><<<1024, 256, 0, stream>>>(
        QbfB, QbfB, KfrA, KfrA, VfrA, VfrA, 1.0f, 4, Rbbf, nullptr);
    gemm_mfma_kernel<<<dim3(8, 32), 256, 0, stream>>>(QAbf, 512, Rbbf, 512, aWft[i],
                                                      abf + (size_t)i * 512, G, 4096, 512);
    ln_kernel<<<4096, 256, 0, stream>>>(G, QA, ag + (size_t)i * 512, ab + (size_t)i * 512,
                                        (i == 1) ? (float*)d_out : QA,
                                        (i == 1) ? nullptr : QAbf);
  }
  (void)in_sizes; (void)n_in; (void)out_size; (void)ws_size;
}

// Round 3
// 1086.823 us; speedup vs baseline: 1.2793x; 1.1474x over previous
//
#include <hip/hip_runtime.h>

#define DEVINL __device__ __forceinline__

typedef short bf16x8 __attribute__((ext_vector_type(8)));
typedef float f32x4 __attribute__((ext_vector_type(4)));

DEVINL unsigned f2b(float f) {  // f32 -> bf16 bits (round to nearest even)
  unsigned u = __float_as_uint(f);
  u = (u + 0x7FFFu + ((u >> 16) & 1u)) >> 16;
  return u & 0xFFFFu;
}
DEVINL uint4 pack8(const float* v) {
  uint4 u;
  u.x = f2b(v[0]) | (f2b(v[1]) << 16);
  u.y = f2b(v[2]) | (f2b(v[3]) << 16);
  u.z = f2b(v[4]) | (f2b(v[5]) << 16);
  u.w = f2b(v[6]) | (f2b(v[7]) << 16);
  return u;
}

// ---------------- reduction helpers ----------------
DEVINL float4 block_sum4(float4 v, float4* sh) {
  const int lane = threadIdx.x & 63, wid = threadIdx.x >> 6;
#pragma unroll
  for (int o = 32; o; o >>= 1) {
    v.x += __shfl_down(v.x, o);
    v.y += __shfl_down(v.y, o);
    v.z += __shfl_down(v.z, o);
    v.w += __shfl_down(v.w, o);
  }
  __syncthreads();
  if (lane == 0) sh[wid] = v;
  __syncthreads();
  float4 a = sh[0], b = sh[1], c = sh[2], d = sh[3], r;
  r.x = a.x + b.x + c.x + d.x;
  r.y = a.y + b.y + c.y + d.y;
  r.z = a.z + b.z + c.z + d.z;
  r.w = a.w + b.w + c.w + d.w;
  return r;
}
DEVINL float block_sum1(float v, float* sh) {
  const int lane = threadIdx.x & 63, wid = threadIdx.x >> 6;
#pragma unroll
  for (int o = 32; o; o >>= 1) v += __shfl_down(v, o);
  __syncthreads();
  if (lane == 0) sh[wid] = v;
  __syncthreads();
  return sh[0] + sh[1] + sh[2] + sh[3];
}

// ---- table projection: P[v,j] = scl*(V[v,:] @ W[:,j]), P[nvec,j] = scl*(bias @ W) ----
__global__ __launch_bounds__(256) void tabproj_kernel(
    const float* __restrict__ V, const float* __restrict__ bias,
    const float* __restrict__ W, float* __restrict__ P, int nvec, float scl) {
  __shared__ float4 sh4[4];
  const int j = blockIdx.x, tid = threadIdx.x;
  float acc[4] = {0.f, 0.f, 0.f, 0.f};
  for (int kk = tid; kk < 512; kk += 256) {
    const float w = W[(size_t)kk * 512 + j];
    for (int v = 0; v < nvec; ++v) acc[v] += V[(size_t)v * 512 + kk] * w;
    acc[3] += bias[kk] * w;
  }
  float4 packed = make_float4(acc[0], acc[1], acc[2], acc[3]);
  packed = block_sum4(packed, sh4);
  if (tid == 0) {
    const float vals[4] = {packed.x * scl, packed.y * scl, packed.z * scl, packed.w * scl};
    for (int v = 0; v < nvec; ++v) P[(size_t)v * 512 + j] = vals[v];
    P[(size_t)nvec * 512 + j] = vals[3];
  }
}

// ---- weight prep: src f32 [K][N] -> dst bf16 [N][K], scaled ----
__global__ __launch_bounds__(256) void transpose_bf_kernel(
    const float* __restrict__ src, unsigned short* __restrict__ dst, int K, int N,
    float scl) {
  __shared__ float tile[32][33];
  const int n0 = blockIdx.x * 32, k0 = blockIdx.y * 32;
  const int tx = threadIdx.x, ty = threadIdx.y;  // 32 x 8
#pragma unroll
  for (int r = 0; r < 4; ++r)
    tile[ty + 8 * r][tx] = src[(size_t)(k0 + ty + 8 * r) * N + n0 + tx];
  __syncthreads();
#pragma unroll
  for (int r = 0; r < 4; ++r)
    dst[(size_t)(n0 + ty + 8 * r) * K + k0 + tx] =
        (unsigned short)f2b(scl * tile[tx][ty + 8 * r]);
}

// ---- V f32 [4096][ld] (head cols at h*D) -> Vfr [bh][sc=32][dtile=D/16][lane][8] ----
__global__ __launch_bounds__(256) void vtrans_frag_kernel(
    const float* __restrict__ V, int ld, int nh, int D,
    unsigned short* __restrict__ Vfr) {
  __shared__ float tile[32][33];
  const int s0 = blockIdx.x * 32, d0 = blockIdx.y * 32;
  const int bh = blockIdx.z;
  const int b = bh / nh, h = bh % nh;
  const int tx = threadIdx.x, ty = threadIdx.y;  // 32 x 8
  const float* src = V + ((size_t)b * 1024 + s0) * ld + h * D + d0;
#pragma unroll
  for (int r = 0; r < 4; ++r)
    tile[ty + 8 * r][tx] = src[(size_t)(ty + 8 * r) * ld + tx];  // [s][d]
  __syncthreads();
  const int idx = ty * 32 + tx;
  if (idx < 128) {
    const int dj = idx & 31, sch = idx >> 5;  // d within tile, s-chunk of 8
    float v[8];
#pragma unroll
    for (int jj = 0; jj < 8; ++jj) v[jj] = tile[sch * 8 + jj][dj];
    const uint4 u = pack8(v);
    const int sc = s0 >> 5;
    const int dtile = (d0 + dj) >> 4;
    const int lane = sch * 16 + (dj & 15);
    *(uint4*)(Vfr + ((size_t)(bh * 32 + sc) * (D / 16) + dtile) * 512 + lane * 8) = u;
  }
}

// ---- cross-side encoder: rank-3 affine -> Kfr + Qbf (packed) + V f32 ----
// nh=2, D=256. Tables T*: rows 0..2 = vectors, row 3 (at +1536) = bias.
__global__ __launch_bounds__(256) void affine3_pack_kernel(
    const float* __restrict__ cx, const float* __restrict__ cy, int sel,
    const float* __restrict__ TK, const float* __restrict__ TV,
    const float* __restrict__ TQ, unsigned short* __restrict__ Kfr,
    unsigned short* __restrict__ Qbf, float* __restrict__ Vf) {
  const int row = blockIdx.x;
  const int b = row >> 10, s = row & 1023;
  const float x = cx[row];
  const float* y = cy + (size_t)row * 8 + 2 * sel;
  const float y0 = y[0], y1 = y[1];
  const int t = threadIdx.x;
  if (t < 128) {
    const bool isQ = t >= 64;
    const int c = t & 63;
    const int h = c >> 5;
    const int d0 = (c & 31) * 8;
    const float* T = isQ ? TQ : TK;
    float v[8];
#pragma unroll
    for (int j = 0; j < 8; ++j) {
      const int col = h * 256 + d0 + j;
      v[j] = x * T[col] + y0 * T[512 + col] + y1 * T[1024 + col] + T[1536 + col];
    }
    const uint4 u = pack8(v);
    const int bh = b * 2 + h;
    if (isQ) {
      *(uint4*)(Qbf + ((size_t)bh * 1024 + s) * 256 + d0) = u;
    } else {
      const int kc = d0 >> 5;
      const int lane = ((d0 & 31) >> 3) * 16 + (s & 15);
      *(uint4*)(Kfr + ((size_t)(bh * 8 + kc) * 64 + (s >> 4)) * 512 + lane * 8) = u;
    }
  } else {
    const int col0 = (t - 128) * 4;
    float4 o;
    float* op = (float*)&o;
#pragma unroll
    for (int j = 0; j < 4; ++j) {
      const int col = col0 + j;
      op[j] = x * TV[col] + y0 * TV[512 + col] + y1 * TV[1024 + col] + TV[1536 + col];
    }
    *(float4*)(Vf + (size_t)row * 512 + col0) = o;
  }
}

// ---- decoder rank-1 producers (nh=4, D=128): T rows [0]=w, [1]=bias ----
__global__ __launch_bounds__(64) void rank1_pack_kernel(
    const float* __restrict__ x, const float* __restrict__ T,
    unsigned short* __restrict__ dst, int isQ) {
  const int row = blockIdx.x;
  const int b = row >> 10, s = row & 1023;
  const float xv = x[row];
  const int c = threadIdx.x;        // 64 chunks of 8
  const int h = c >> 4;             // 16 chunks per head
  const int d0 = (c & 15) * 8;
  float v[8];
#pragma unroll
  for (int j = 0; j < 8; ++j) {
    const int col = h * 128 + d0 + j;
    v[j] = xv * T[col] + T[512 + col];
  }
  const uint4 u = pack8(v);
  const int bh = b * 4 + h;
  if (isQ) {
    *(uint4*)(dst + ((size_t)bh * 1024 + s) * 128 + d0) = u;
  } else {
    const int kc = d0 >> 5;
    const int lane = ((d0 & 31) >> 3) * 16 + (s & 15);
    *(uint4*)(dst + ((size_t)(bh * 4 + kc) * 64 + (s >> 4)) * 512 + lane * 8) = u;
  }
}

// ---- out[r,:] = cx[r]*W3[0,:] + y0*W3[1,:] + y1*W3[2,:] + bias (f32 + bf16) ----
__global__ __launch_bounds__(512) void affine3_kernel(
    const float* __restrict__ cx, const float* __restrict__ cy, int sel,
    const float* __restrict__ W3, const float* __restrict__ bias,
    float* __restrict__ out, unsigned short* __restrict__ outb) {
  const int r = blockIdx.x, j = threadIdx.x;
  const float* y = cy + (size_t)r * 8 + 2 * sel;
  const float v = cx[r] * W3[j] + y[0] * W3[512 + j] + y[1] * W3[1024 + j] + bias[j];
  if (out) out[(size_t)r * 512 + j] = v;
  if (outb) outb[(size_t)r * 512 + j] = (unsigned short)f2b(v);
}

// ---- out[r,:] = x[r]*w + b ----
__global__ __launch_bounds__(512) void rank1_kernel(
    const float* __restrict__ x, const float* __restrict__ w,
    const float* __restrict__ b, float* __restrict__ out,
    unsigned short* __restrict__ outb) {
  const int r = blockIdx.x, j = threadIdx.x;
  const float v = x[r] * w[j] + b[j];
  if (out) out[(size_t)r * 512 + j] = v;
  if (outb) outb[(size_t)r * 512 + j] = (unsigned short)f2b(v);
}

// ------------- MFMA GEMM (double-buffered): C = [A0 | A1] @ Wt^T (+bias) ---------
__global__ __launch_bounds__(256) void gemm_mfma_kernel(
    const unsigned short* __restrict__ A0, int K0,
    const unsigned short* __restrict__ A1, int K1,
    const unsigned short* __restrict__ Wt, const float* __restrict__ bias,
    float* __restrict__ C, int M, int N) {
  constexpr int BM = 128, BN = 64, BK = 32, LDP = 40;
  __shared__ unsigned short As[2][BM * LDP];
  __shared__ unsigned short Bs[2][BN * LDP];
  const int tid = threadIdx.x;
  const int lane = tid & 63, w = tid >> 6;
  const int bm = blockIdx.y * BM, bn = blockIdx.x * BN;
  const int wm = (w & 1) * 64, wn = (w >> 1) * 32;
  const int l15 = lane & 15, lq = lane >> 4;
  const int ar = tid >> 1, ac = (tid & 1) * 16;
  const int br = tid >> 2, bc = (tid & 3) * 8;
  const int Ktot = K0 + K1;
  f32x4 acc[4][2] = {};
  uint4 ra0, ra1, rb0;
#define GLOAD(k0_)                                                         \
  do {                                                                     \
    const unsigned short* A_;                                              \
    int kk_, Ak_;                                                          \
    if ((k0_) < K0) { A_ = A0; kk_ = (k0_); Ak_ = K0; }                    \
    else            { A_ = A1; kk_ = (k0_) - K0; Ak_ = K1; }               \
    ra0 = *(const uint4*)(A_ + (size_t)(bm + ar) * Ak_ + kk_ + ac);        \
    ra1 = *(const uint4*)(A_ + (size_t)(bm + ar) * Ak_ + kk_ + ac + 8);    \
    rb0 = *(const uint4*)(Wt + (size_t)(bn + br) * Ktot + (k0_) + bc);     \
  } while (0)
  GLOAD(0);
  *(uint4*)(As[0] + ar * LDP + ac) = ra0;
  *(uint4*)(As[0] + ar * LDP + ac + 8) = ra1;
  *(uint4*)(Bs[0] + br * LDP + bc) = rb0;
  __syncthreads();
  int buf = 0;
  for (int k0 = 0; k0 < Ktot; k0 += BK) {
    const bool more = (k0 + BK) < Ktot;
    if (more) GLOAD(k0 + BK);
    bf16x8 af[4], bfr[2];
#pragma unroll
    for (int mt = 0; mt < 4; ++mt)
      af[mt] = *(const bf16x8*)(As[buf] + (wm + mt * 16 + l15) * LDP + lq * 8);
#pragma unroll
    for (int nt = 0; nt < 2; ++nt)
      bfr[nt] = *(const bf16x8*)(Bs[buf] + (wn + nt * 16 + l15) * LDP + lq * 8);
#pragma unroll
    for (int mt = 0; mt < 4; ++mt)
#pragma unroll
      for (int nt = 0; nt < 2; ++nt)
        acc[mt][nt] =
            __builtin_amdgcn_mfma_f32_16x16x32_bf16(af[mt], bfr[nt], acc[mt][nt], 0, 0, 0);
    if (more) {
      *(uint4*)(As[buf ^ 1] + ar * LDP + ac) = ra0;
      *(uint4*)(As[buf ^ 1] + ar * LDP + ac + 8) = ra1;
      *(uint4*)(Bs[buf ^ 1] + br * LDP + bc) = rb0;
    }
    __syncthreads();
    buf ^= 1;
  }
#undef GLOAD
#pragma unroll
  for (int nt = 0; nt < 2; ++nt) {
    const int col = bn + wn + nt * 16 + l15;
    const float bv = bias ? bias[col] : 0.f;
#pragma unroll
    for (int mt = 0; mt < 4; ++mt) {
#pragma unroll
      for (int r = 0; r < 4; ++r) {
        const int row = bm + wm + mt * 16 + lq * 4 + r;
        C[(size_t)row * N + col] = acc[mt][nt][r] + bv;
      }
    }
  }
}

// ------- MFMA GEMM with fused frag-pack epilogue (K=512, single A) ---------------
// MODE 0: N=1536 = K|V|Q sections, nh=2, D=256 -> Kfr, Vfr, Qbf
// MODE 1: N=512  = V only, nh=4, D=128 -> Vfr
// MODE 2: N=512  = Q only, nh=4, D=128 -> Qbf (weights pre-scaled)
template <int MODE>
__global__ __launch_bounds__(256) void gemm_pack_kernel(
    const unsigned short* __restrict__ A0, const unsigned short* __restrict__ Wt,
    unsigned short* __restrict__ Kfr, unsigned short* __restrict__ Vfr,
    unsigned short* __restrict__ Qbf) {
  constexpr int BM = 128, BN = 64, BK = 32, LDP = 40, K = 512;
  __shared__ unsigned short As[2][BM * LDP];
  __shared__ unsigned short Bs[2][BN * LDP];
  const int tid = threadIdx.x;
  const int lane = tid & 63, w = tid >> 6;
  const int bm = blockIdx.y * BM, bn = blockIdx.x * BN;
  const int wm = (w & 1) * 64, wn = (w >> 1) * 32;
  const int l15 = lane & 15, lq = lane >> 4;
  const int ar = tid >> 1, ac = (tid & 1) * 16;
  const int br = tid >> 2, bc = (tid & 3) * 8;
  f32x4 acc[4][2] = {};
  uint4 ra0 = *(const uint4*)(A0 + (size_t)(bm + ar) * K + ac);
  uint4 ra1 = *(const uint4*)(A0 + (size_t)(bm + ar) * K + ac + 8);
  uint4 rb0 = *(const uint4*)(Wt + (size_t)(bn + br) * K + bc);
  *(uint4*)(As[0] + ar * LDP + ac) = ra0;
  *(uint4*)(As[0] + ar * LDP + ac + 8) = ra1;
  *(uint4*)(Bs[0] + br * LDP + bc) = rb0;
  __syncthreads();
  int buf = 0;
  for (int k0 = 0; k0 < K; k0 += BK) {
    const bool more = (k0 + BK) < K;
    if (more) {
      ra0 = *(const uint4*)(A0 + (size_t)(bm + ar) * K + k0 + BK + ac);
      ra1 = *(const uint4*)(A0 + (size_t)(bm + ar) * K + k0 + BK + ac + 8);
      rb0 = *(const uint4*)(Wt + (size_t)(bn + br) * K + k0 + BK + bc);
    }
    bf16x8 af[4], bfr[2];
#pragma unroll
    for (int mt = 0; mt < 4; ++mt)
      af[mt] = *(const bf16x8*)(As[buf] + (wm + mt * 16 + l15) * LDP + lq * 8);
#pragma unroll
    for (int nt = 0; nt < 2; ++nt)
      bfr[nt] = *(const bf16x8*)(Bs[buf] + (wn + nt * 16 + l15) * LDP + lq * 8);
#pragma unroll
    for (int mt = 0; mt < 4; ++mt)
#pragma unroll
      for (int nt = 0; nt < 2; ++nt)
        acc[mt][nt] =
            __builtin_amdgcn_mfma_f32_16x16x32_bf16(af[mt], bfr[nt], acc[mt][nt], 0, 0, 0);
    if (more) {
      *(uint4*)(As[buf ^ 1] + ar * LDP + ac) = ra0;
      *(uint4*)(As[buf ^ 1] + ar * LDP + ac + 8) = ra1;
      *(uint4*)(Bs[buf ^ 1] + br * LDP + bc) = rb0;
    }
    __syncthreads();
    buf ^= 1;
  }
  // ---- fused pack epilogue (element mappings match pack_kq/vtrans/qpack) ----
  const int b = bm >> 10;                       // BM=128 divides 1024
  const int s0base = (bm & 1023) + wm + lq * 4;
#pragma unroll
  for (int nt = 0; nt < 2; ++nt) {
    const int col = bn + wn + nt * 16 + l15;
    int sec, h, d, nh2, Dv;
    if constexpr (MODE == 0) {
      sec = col >> 9; const int c = col & 511; h = c >> 8; d = c & 255; nh2 = 2; Dv = 256;
    } else if constexpr (MODE == 1) {
      sec = 1; h = col >> 7; d = col & 127; nh2 = 4; Dv = 128;
    } else {
      sec = 2; h = col >> 7; d = col & 127; nh2 = 4; Dv = 128;
    }
    const int bh = b * nh2 + h;
#pragma unroll
    for (int mt = 0; mt < 4; ++mt) {
      const int s0 = s0base + mt * 16;          // 4 consecutive s: s0..s0+3
      const float* a = (const float*)&acc[mt][nt];
      if (sec == 2) {                           // Q: [bh][s][Dv]
        unsigned short* q = Qbf + ((size_t)bh * 1024 + s0) * Dv + d;
#pragma unroll
        for (int r = 0; r < 4; ++r) q[(size_t)r * Dv] = (unsigned short)f2b(a[r]);
      } else if (sec == 0) {                    // K frag: B-operand layout
        unsigned short* kp = Kfr +
            ((size_t)(bh * 8 + (d >> 5)) * 64 + (s0 >> 4)) * 512 +
            ((d & 31) >> 3) * 128 + (d & 7);
#pragma unroll
        for (int r = 0; r < 4; ++r)
          kp[((s0 & 15) + r) * 8] = (unsigned short)f2b(a[r]);
      } else {                                  // V frag: B-operand layout
        unsigned short* vp = Vfr +
            ((size_t)(bh * 32 + (s0 >> 5)) * (Dv / 16) + (d >> 4)) * 512 +
            (((s0 >> 3) & 3) * 16 + (d & 15)) * 8 + (s0 & 7);
        uint2 u;
        u.x = f2b(a[0]) | (f2b(a[1]) << 16);
        u.y = f2b(a[2]) | (f2b(a[3]) << 16);
        *(uint2*)vp = u;
      }
    }
  }
}

// ---------------- MFMA flash attention, frag-packed inputs -----------------------
// Block = 16 q rows of one (b,head) vs ONE KV side; 4 waves own 256 keys each.
// Q pre-scaled.  No max-subtraction (LN-normalized inputs keep |score| small).
// NKV==2: grid = 2*512, side = blockIdx>>9; writes f32 partials to Rp.
// NKV==1: writes bf16 directly with post_scale.
template <int D, int NKV>
__global__ __launch_bounds__(256, 2) void attn_mfma_kernel(
    const unsigned short* __restrict__ Qa, const unsigned short* __restrict__ Qb,
    const unsigned short* __restrict__ KfrA, const unsigned short* __restrict__ KfrB,
    const unsigned short* __restrict__ VfrA, const unsigned short* __restrict__ VfrB,
    float post_scale, int nh, unsigned short* __restrict__ R,
    float* __restrict__ Rp) {
  constexpr int NQS = NKV;
  constexpr int QP = D + 8;
  constexpr int WP = 1024 + 8;
  constexpr int DT = D / 64;
  const int tid = threadIdx.x;
  const int lane = tid & 63, w = tid >> 6;
  const int l15 = lane & 15, lq = lane >> 4;
  const int nbh = 4 * nh;
  int bx = blockIdx.x;
  int side = 0;
  if constexpr (NKV == 2) { side = bx >> 9; bx &= 511; }
  const int bh = bx % nbh;                   // XCD-local (b,h)
  const int qb16 = (bx / nbh) * 16;
  const int b = bh / nh, head = bh % nh;
  const size_t rowb = (size_t)b * 1024;
  const int colo = head * D;

  __shared__ unsigned short qsh[NQS * 16 * QP];
  __shared__ unsigned short wsh[16 * WP];
  __shared__ float redA[4][16];
  __shared__ float redB[4][16];

  // ---- stage Q tiles ----
  for (int idx = tid; idx < NQS * 16 * (D / 8); idx += 256) {
    const int st = idx / (16 * (D / 8));
    const int rem = idx - st * 16 * (D / 8);
    const int r = rem / (D / 8), ch = rem - r * (D / 8);
    const unsigned short* Q = st ? Qb : Qa;
    const uint4 u = *(const uint4*)(Q + ((size_t)bh * 1024 + qb16 + r) * D + ch * 8);
    *(uint4*)(qsh + st * 16 * QP + r * QP + ch * 8) = u;
  }
  __syncthreads();

  const unsigned short* Kp = (side ? KfrB : KfrA) + (size_t)bh * ((size_t)D * 1024);
  const unsigned short* Vp = (side ? VfrB : VfrA) + (size_t)bh * ((size_t)D * 1024);

  // ---- QK^T ----
  f32x4 acc[NQS][16] = {};
#pragma unroll 1
  for (int kc = 0; kc < D / 32; ++kc) {
    bf16x8 kf[16];
#pragma unroll
    for (int st = 0; st < 16; ++st)
      kf[st] = *(const bf16x8*)(Kp + ((size_t)kc * 64 + w * 16 + st) * 512 + lane * 8);
    const bf16x8 qa = *(const bf16x8*)(qsh + l15 * QP + kc * 32 + lq * 8);
    __builtin_amdgcn_s_setprio(1);
#pragma unroll
    for (int st = 0; st < 16; ++st)
      acc[0][st] = __builtin_amdgcn_mfma_f32_16x16x32_bf16(qa, kf[st], acc[0][st], 0, 0, 0);
    __builtin_amdgcn_s_setprio(0);
    if constexpr (NQS == 2) {
      const bf16x8 qb2 = *(const bf16x8*)(qsh + 16 * QP + l15 * QP + kc * 32 + lq * 8);
      __builtin_amdgcn_s_setprio(1);
#pragma unroll
      for (int st = 0; st < 16; ++st)
        acc[1][st] =
            __builtin_amdgcn_mfma_f32_16x16x32_bf16(qb2, kf[st], acc[1][st], 0, 0, 0);
      __builtin_amdgcn_s_setprio(0);
    }
  }

  // ---- exp (no max shift) + row sum ----
  float psA[4] = {0.f, 0.f, 0.f, 0.f}, psB[4] = {0.f, 0.f, 0.f, 0.f};
#pragma unroll
  for (int st = 0; st < 16; ++st)
#pragma unroll
    for (int r = 0; r < 4; ++r) {
      acc[0][st][r] = __expf(acc[0][st][r]);
      psA[r] += acc[0][st][r];
      if constexpr (NQS == 2) {
        acc[1][st][r] = __expf(acc[1][st][r]);
        psB[r] += acc[1][st][r];
      }
    }
#pragma unroll
  for (int o = 1; o < 16; o <<= 1)
#pragma unroll
    for (int r = 0; r < 4; ++r) {
      psA[r] += __shfl_xor(psA[r], o);
      if constexpr (NQS == 2) psB[r] += __shfl_xor(psB[r], o);
    }
  if (l15 == 0) {
#pragma unroll
    for (int r = 0; r < 4; ++r) {
      redA[w][lq * 4 + r] = psA[r];
      if constexpr (NQS == 2) redB[w][lq * 4 + r] = psB[r];
    }
  }
  __syncthreads();
  float invA[4], invB[4];
#pragma unroll
  for (int r = 0; r < 4; ++r) {
    invA[r] = 1.f / (redA[0][lq * 4 + r] + redA[1][lq * 4 + r] +
                     redA[2][lq * 4 + r] + redA[3][lq * 4 + r]);
    if constexpr (NQS == 2)
      invB[r] = 1.f / (redB[0][lq * 4 + r] + redB[1][lq * 4 + r] +
                       redB[2][lq * 4 + r] + redB[3][lq * 4 + r]);
  }
  // ---- combined weight strip ----
#pragma unroll
  for (int st = 0; st < 16; ++st)
#pragma unroll
    for (int r = 0; r < 4; ++r) {
      float wv = acc[0][st][r] * invA[r];
      if constexpr (NQS == 2) wv += acc[1][st][r] * invB[r];
      wsh[(lq * 4 + r) * WP + w * 256 + st * 16 + l15] = (unsigned short)f2b(wv);
    }
  __syncthreads();

  // ---- PV ----
  f32x4 acc_o[DT] = {};
#pragma unroll 1
  for (int sc = 0; sc < 32; sc += 2) {
    bf16x8 pa[2], vb[2][DT];
#pragma unroll
    for (int u = 0; u < 2; ++u) {
      pa[u] = *(const bf16x8*)(wsh + l15 * WP + (sc + u) * 32 + lq * 8);
#pragma unroll
      for (int dt = 0; dt < DT; ++dt)
        vb[u][dt] = *(const bf16x8*)(
            Vp + ((size_t)(sc + u) * (D / 16) + w * DT + dt) * 512 + lane * 8);
    }
    __builtin_amdgcn_s_setprio(1);
#pragma unroll
    for (int u = 0; u < 2; ++u)
#pragma unroll
      for (int dt = 0; dt < DT; ++dt)
        acc_o[dt] =
            __builtin_amdgcn_mfma_f32_16x16x32_bf16(pa[u], vb[u][dt], acc_o[dt], 0, 0, 0);
    __builtin_amdgcn_s_setprio(0);
  }

  // ---- epilogue ----
  if constexpr (NKV == 2) {
    float* dst = Rp + (size_t)side * (4096 * 512) + (rowb + qb16) * 512 + colo;
#pragma unroll
    for (int dt = 0; dt < DT; ++dt)
#pragma unroll
      for (int r = 0; r < 4; ++r) {
        const int q = lq * 4 + r;
        const int d = w * (DT * 16) + dt * 16 + l15;
        dst[(size_t)q * 512 + d] = acc_o[dt][r];
      }
  } else {
#pragma unroll
    for (int dt = 0; dt < DT; ++dt)
#pragma unroll
      for (int r = 0; r < 4; ++r) {
        const int q = lq * 4 + r;
        const int d = w * (DT * 16) + dt * 16 + l15;
        R[(rowb + qb16 + q) * 512 + colo + d] =
            (unsigned short)f2b(acc_o[dt][r] * post_scale);
      }
  }
}

// ---- combine side partials: O = bf16(A + B), 8 elems/thread ----
__global__ __launch_bounds__(256) void addcvt_kernel(
    const float* __restrict__ A, const float* __restrict__ B,
    unsigned short* __restrict__ O) {
  const size_t i = ((size_t)blockIdx.x * 256 + threadIdx.x) * 8;
  float v[8];
  *(float4*)v = *(const float4*)(A + i);
  *(float4*)(v + 4) = *(const float4*)(A + i + 4);
  const float4 b0 = *(const float4*)(B + i);
  const float4 b1 = *(const float4*)(B + i + 4);
  v[0] += b0.x; v[1] += b0.y; v[2] += b0.z; v[3] += b0.w;
  v[4] += b1.x; v[5] += b1.y; v[6] += b1.z; v[7] += b1.w;
  *(uint4*)(O + i) = pack8(v);
}

// ------------- out = LayerNorm(G + res) * g + b  (f32 out + optional bf16 out) ----
__global__ __launch_bounds__(256) void ln_kernel(
    const float* __restrict__ G, const float* __restrict__ res,
    const float* __restrict__ g, const float* __restrict__ b,
    float* __restrict__ out, unsigned short* __restrict__ outb) {
  __shared__ float sh[4];
  const int row = blockIdx.x, tid = threadIdx.x;
  const size_t off = (size_t)row * 512;
  const float x0 = G[off + tid] + res[off + tid];
  const float x1 = G[off + tid + 256] + res[off + tid + 256];
  const float mean = block_sum1(x0 + x1, sh) * (1.0f / 512.0f);
  const float d0 = x0 - mean, d1 = x1 - mean;
  const float var = block_sum1(d0 * d0 + d1 * d1, sh) * (1.0f / 512.0f);
  const float inv = rsqrtf(var + 1e-5f);
  const float y0 = d0 * inv * g[tid] + b[tid];
  const float y1 = d1 * inv * g[tid + 256] + b[tid + 256];
  out[off + tid] = y0;
  out[off + tid + 256] = y1;
  if (outb) {
    outb[off + tid] = (unsigned short)f2b(y0);
    outb[off + tid + 256] = (unsigned short)f2b(y1);
  }
}

extern "C" void kernel_launch(void* const* d_in, const int* in_sizes, int n_in,
                              void* d_out, int out_size, void* d_ws, size_t ws_size,
                              hipStream_t stream) {
  typedef unsigned short ushort_t;
  const float* cx   = (const float*)d_in[0];
  const float* cy   = (const float*)d_in[1];
  const float* txp  = (const float*)d_in[2];
  const float* in_W = (const float*)d_in[3];
  const float* in_b = (const float*)d_in[4];
  const float* cx_W = (const float*)d_in[5];
  const float* cx_b = (const float*)d_in[6];
  const float* tx_W = (const float*)d_in[7];
  const float* tx_b = (const float*)d_in[8];
  const float* sWk  = (const float*)d_in[9];
  const float* sWv  = (const float*)d_in[10];
  const float* sWq  = (const float*)d_in[11];
  const float* sWf  = (const float*)d_in[12];
  const float* sbf  = (const float*)d_in[13];
  const float* sg   = (const float*)d_in[14];
  const float* sb   = (const float*)d_in[15];
  const float* aWk  = (const float*)d_in[16];
  const float* aWv  = (const float*)d_in[17];
  const float* aWq  = (const float*)d_in[18];
  const float* aWf  = (const float*)d_in[19];
  const float* abf  = (const float*)d_in[20];
  const float* ag   = (const float*)d_in[21];
  const float* ab   = (const float*)d_in[22];

  const float SSC = 0.0625f;               // 1/sqrt(256)
  const float CSC = 0.08838834764831845f;  // 1/sqrt(128)

  const size_t MB = 1024 * 1024;
  char* ws = (char*)d_ws;
  float*    E     = (float*)(ws + 0 * MB);       // 8 MB
  ushort_t* Ebf   = (ushort_t*)(ws + 8 * MB);    // 4 MB
  float*    QA    = (float*)(ws + 12 * MB);      // 8 MB
  ushort_t* QAbf  = (ushort_t*)(ws + 20 * MB);   // 4 MB
  ushort_t* Rbbf  = (ushort_t*)(ws + 24 * MB);   // 4 MB
  float*    G     = (float*)(ws + 28 * MB);      // 8 MB (Wf GEMM out)
  float*    Rp    = G;                            // alias: attn f32 partials (2x8MB)
                                                  //   drained by addcvt before G write
  ushort_t* KfrA  = (ushort_t*)(ws + 52 * MB);   // 4 MB
  ushort_t* VfrA  = (ushort_t*)(ws + 56 * MB);   // 4 MB
  ushort_t* QbfA  = (ushort_t*)(ws + 60 * MB);   // 4 MB
  ushort_t* KfrB  = (ushort_t*)(ws + 64 * MB);   // 4 MB
  ushort_t* VfrB  = (ushort_t*)(ws + 68 * MB);   // 4 MB
  ushort_t* QbfB  = (ushort_t*)(ws + 72 * MB);   // 4 MB
  float*    cVf   = (float*)(ws + 76 * MB);      // 8 MB cross V f32
  ushort_t* Wkvqt[2] = {(ushort_t*)(ws + 92 * MB),
                        (ushort_t*)(ws + 92 * MB + 1536 * 1024)};
  ushort_t* Wft[2]   = {(ushort_t*)(ws + 95 * MB), (ushort_t*)(ws + 96 * MB)};
  ushort_t* aWvt[2]  = {(ushort_t*)(ws + 97 * MB),
                        (ushort_t*)(ws + 97 * MB + 512 * 1024)};
  ushort_t* aWqt1    = (ushort_t*)(ws + 98 * MB);
  ushort_t* aWft[2]  = {(ushort_t*)(ws + 99 * MB), (ushort_t*)(ws + 100 * MB)};
  float*    Ttab     = (float*)(ws + 101 * MB);

  float* T_sc[2][3];
  for (int i = 0; i < 2; ++i)
    for (int w = 0; w < 3; ++w) T_sc[i][w] = Ttab + (size_t)(i * 3 + w) * 2048;
  float* T_cak[2] = {Ttab + 12288, Ttab + 12288 + 1024};
  float* T_caq0 = Ttab + 14336;

  const dim3 tb(32, 8);
  const dim3 tg512(16, 16), tg1024(16, 32);

  // ---- prep: weight transposes + projection tables (Q weights pre-scaled) ----
  for (int i = 0; i < 2; ++i) {
    transpose_bf_kernel<<<tg512, tb, 0, stream>>>(sWk + (size_t)i * 262144, Wkvqt[i], 512, 512, 1.f);
    transpose_bf_kernel<<<tg512, tb, 0, stream>>>(sWv + (size_t)i * 262144, Wkvqt[i] + 512 * 512, 512, 512, 1.f);
    transpose_bf_kernel<<<tg512, tb, 0, stream>>>(sWq + (size_t)i * 262144, Wkvqt[i] + 1024 * 512, 512, 512, SSC);
    transpose_bf_kernel<<<tg1024, tb, 0, stream>>>(sWf + (size_t)i * 524288, Wft[i], 1024, 512, 1.f);
    transpose_bf_kernel<<<tg512, tb, 0, stream>>>(aWv + (size_t)i * 262144, aWvt[i], 512, 512, 1.f);
    transpose_bf_kernel<<<tg1024, tb, 0, stream>>>(aWf + (size_t)i * 524288, aWft[i], 1024, 512, 1.f);
    tabproj_kernel<<<512, 256, 0, stream>>>(in_W, in_b, sWk + (size_t)i * 262144, T_sc[i][0], 3, 1.f);
    tabproj_kernel<<<512, 256, 0, stream>>>(in_W, in_b, sWv + (size_t)i * 262144, T_sc[i][1], 3, 1.f);
    tabproj_kernel<<<512, 256, 0, stream>>>(in_W, in_b, sWq + (size_t)i * 262144, T_sc[i][2], 3, SSC);
    tabproj_kernel<<<512, 256, 0, stream>>>(cx_W, cx_b, aWk + (size_t)i * 262144, T_cak[i], 1, 1.f);
  }
  transpose_bf_kernel<<<tg512, tb, 0, stream>>>(aWq + 262144, aWqt1, 512, 512, CSC);
  tabproj_kernel<<<512, 256, 0, stream>>>(tx_W, tx_b, aWq, T_caq0, 1, CSC);

  // ---- initial activations ----
  affine3_kernel<<<4096, 512, 0, stream>>>(cx, cy, 0, in_W, in_b, E, Ebf);
  rank1_kernel<<<4096, 512, 0, stream>>>(txp, tx_W, tx_b, QA, QAbf);

  // ---- 8 self/cross encoder layers ----
  for (int p = 0; p < 4; ++p) {
    for (int i = 0; i < 2; ++i) {
      gemm_pack_kernel<0><<<dim3(24, 32), 256, 0, stream>>>(Ebf, Wkvqt[i], KfrA, VfrA,
                                                            QbfA);
      if (p > 0) {
        affine3_pack_kernel<<<4096, 256, 0, stream>>>(cx, cy, p, T_sc[i][0], T_sc[i][1],
                                                      T_sc[i][2], KfrB, QbfB, cVf);
        vtrans_frag_kernel<<<dim3(32, 8, 8), tb, 0, stream>>>(cVf, 512, 2, 256, VfrB);
        attn_mfma_kernel<256, 2><<<1024, 256, 0, stream>>>(
            QbfA, QbfB, KfrA, KfrB, VfrA, VfrB, 1.0f, 2, nullptr, Rp);
        addcvt_kernel<<<1024, 256, 0, stream>>>(Rp, Rp + 4096 * 512, Rbbf);
      } else {
        // x2 is x: 4 identical sdpa terms -> 4 * sdpa(sQ,sK,sV)
        attn_mfma_kernel<256, 1><<<512, 256, 0, stream>>>(
            QbfA, QbfA, KfrA, KfrA, VfrA, VfrA, 4.0f, 2, Rbbf, nullptr);
      }
      gemm_mfma_kernel<<<dim3(8, 32), 256, 0, stream>>>(Ebf, 512, Rbbf, 512, Wft[i],
                                                        sbf + (size_t)i * 512, G, 4096, 512);
      ln_kernel<<<4096, 256, 0, stream>>>(G, E, sg + (size_t)i * 512, sb + (size_t)i * 512,
                                          E, Ebf);
    }
  }

  // ---- 2 cross-attention decoder layers (nh=4, D=128) ----
  for (int i = 0; i < 2; ++i) {
    rank1_pack_kernel<<<4096, 64, 0, stream>>>(cx, T_cak[i], KfrA, 0);
    gemm_pack_kernel<1><<<dim3(8, 32), 256, 0, stream>>>(Ebf, aWvt[i], nullptr, VfrA,
                                                         nullptr);
    if (i == 0) {
      rank1_pack_kernel<<<4096, 64, 0, stream>>>(txp, T_caq0, QbfB, 1);
    } else {
      gemm_pack_kernel<2><<<dim3(8, 32), 256, 0, stream>>>(QAbf, aWqt1, nullptr, nullptr,
                                                           QbfB);
    }
    attn_mfma_kernel<128, 1><<<1024, 256, 0, stream>>>(
        QbfB, QbfB, KfrA, KfrA, VfrA, VfrA, 1.0f, 4, Rbbf, nullptr);
    gemm_mfma_kernel<<<dim3(8, 32), 256, 0, stream>>>(QAbf, 512, Rbbf, 512, aWft[i],
                                                      abf + (size_t)i * 512, G, 4096, 512);
    ln_kernel<<<4096, 256, 0, stream>>>(G, QA, ag + (size_t)i * 512, ab + (size_t)i * 512,
                                        (i == 1) ? (float*)d_out : QA,
                                        (i == 1) ? nullptr : QAbf);
  }
  (void)in_sizes; (void)n_in; (void)out_size; (void)ws_size;
}

// Round 5
// 1059.863 us; speedup vs baseline: 1.3118x; 1.0254x over previous
//
#include <hip/hip_runtime.h>

#define DEVINL __device__ __forceinline__

typedef short bf16x8 __attribute__((ext_vector_type(8)));
typedef float f32x4 __attribute__((ext_vector_type(4)));

DEVINL unsigned f2b(float f) {  // f32 -> bf16 bits (round to nearest even)
  unsigned u = __float_as_uint(f);
  u = (u + 0x7FFFu + ((u >> 16) & 1u)) >> 16;
  return u & 0xFFFFu;
}
DEVINL uint4 pack8(const float* v) {
  uint4 u;
  u.x = f2b(v[0]) | (f2b(v[1]) << 16);
  u.y = f2b(v[2]) | (f2b(v[3]) << 16);
  u.z = f2b(v[4]) | (f2b(v[5]) << 16);
  u.w = f2b(v[6]) | (f2b(v[7]) << 16);
  return u;
}

// ---------------- reduction helpers ----------------
DEVINL float4 block_sum4(float4 v, float4* sh) {
  const int lane = threadIdx.x & 63, wid = threadIdx.x >> 6;
#pragma unroll
  for (int o = 32; o; o >>= 1) {
    v.x += __shfl_down(v.x, o);
    v.y += __shfl_down(v.y, o);
    v.z += __shfl_down(v.z, o);
    v.w += __shfl_down(v.w, o);
  }
  __syncthreads();
  if (lane == 0) sh[wid] = v;
  __syncthreads();
  float4 a = sh[0], b = sh[1], c = sh[2], d = sh[3], r;
  r.x = a.x + b.x + c.x + d.x;
  r.y = a.y + b.y + c.y + d.y;
  r.z = a.z + b.z + c.z + d.z;
  r.w = a.w + b.w + c.w + d.w;
  return r;
}
DEVINL float block_sum1(float v, float* sh) {
  const int lane = threadIdx.x & 63, wid = threadIdx.x >> 6;
#pragma unroll
  for (int o = 32; o; o >>= 1) v += __shfl_down(v, o);
  __syncthreads();
  if (lane == 0) sh[wid] = v;
  __syncthreads();
  return sh[0] + sh[1] + sh[2] + sh[3];
}

// ---- fused table projections (9 jobs via blockIdx.y) ----
// z 0..5: (in_W,in_b) nvec=3, W = {sWk,sWv,sWq}[z%3] + (z/3)*262144, P = Ttab+z*2048,
//         scl = SSC when z%3==2.
// z 6..7: (cx_W,cx_b) nvec=1, W = aWk + (z-6)*262144, P = Ttab+12288+(z-6)*1024.
// z 8   : (tx_W,tx_b) nvec=1, W = aWq, P = Ttab+14336, scl = CSC.
__global__ __launch_bounds__(256) void tabproj9_kernel(
    const float* __restrict__ in_W, const float* __restrict__ in_b,
    const float* __restrict__ cx_W, const float* __restrict__ cx_b,
    const float* __restrict__ tx_W, const float* __restrict__ tx_b,
    const float* __restrict__ sWk, const float* __restrict__ sWv,
    const float* __restrict__ sWq, const float* __restrict__ aWk,
    const float* __restrict__ aWq, float* __restrict__ Ttab) {
  const int z = blockIdx.y;
  const float* V;
  const float* bias;
  const float* W;
  float* P;
  int nvec;
  float scl = 1.f;
  if (z < 6) {
    V = in_W; bias = in_b; nvec = 3;
    const int i = z / 3, wsel = z % 3;
    W = (wsel == 0 ? sWk : wsel == 1 ? sWv : sWq) + (size_t)i * 262144;
    P = Ttab + (size_t)z * 2048;
    if (wsel == 2) scl = 0.0625f;
  } else if (z < 8) {
    V = cx_W; bias = cx_b; nvec = 1;
    W = aWk + (size_t)(z - 6) * 262144;
    P = Ttab + 12288 + (size_t)(z - 6) * 1024;
  } else {
    V = tx_W; bias = tx_b; nvec = 1;
    W = aWq; P = Ttab + 14336; scl = 0.08838834764831845f;
  }
  __shared__ float4 sh4[4];
  const int j = blockIdx.x, tid = threadIdx.x;
  float acc[4] = {0.f, 0.f, 0.f, 0.f};
  for (int kk = tid; kk < 512; kk += 256) {
    const float w = W[(size_t)kk * 512 + j];
    for (int v = 0; v < nvec; ++v) acc[v] += V[(size_t)v * 512 + kk] * w;
    acc[3] += bias[kk] * w;
  }
  float4 packed = make_float4(acc[0], acc[1], acc[2], acc[3]);
  packed = block_sum4(packed, sh4);
  if (tid == 0) {
    const float vals[4] = {packed.x * scl, packed.y * scl, packed.z * scl, packed.w * scl};
    for (int v = 0; v < nvec; ++v) P[(size_t)v * 512 + j] = vals[v];
    P[(size_t)nvec * 512 + j] = vals[3];
  }
}

// ---- fused weight transposes, K=512 (9 jobs via blockIdx.z) ----
// z 0..5: {sWk,sWv,sWq}[z%3] + (z/3)*262144 -> Wkvqt0 + (z/3)*786432 + (z%3)*262144,
//         scl = SSC when z%3==2.
// z 6..7: aWv + (z-6)*262144 -> aWvt0 + (z-6)*262144.
// z 8   : aWq + 262144 -> aWqt1, scl = CSC.
__global__ __launch_bounds__(256) void transpose_kvq_kernel(
    const float* __restrict__ sWk, const float* __restrict__ sWv,
    const float* __restrict__ sWq, const float* __restrict__ aWv,
    const float* __restrict__ aWq, unsigned short* __restrict__ Wkvqt0,
    unsigned short* __restrict__ aWvt0, unsigned short* __restrict__ aWqt1) {
  const int z = blockIdx.z;
  const float* src;
  unsigned short* dst;
  float scl = 1.f;
  if (z < 6) {
    const int i = z / 3, wsel = z % 3;
    src = (wsel == 0 ? sWk : wsel == 1 ? sWv : sWq) + (size_t)i * 262144;
    dst = Wkvqt0 + (size_t)i * 786432 + (size_t)wsel * 262144;
    if (wsel == 2) scl = 0.0625f;
  } else if (z < 8) {
    src = aWv + (size_t)(z - 6) * 262144;
    dst = aWvt0 + (size_t)(z - 6) * 262144;
  } else {
    src = aWq + 262144; dst = aWqt1; scl = 0.08838834764831845f;
  }
  __shared__ float tile[32][33];
  const int n0 = blockIdx.x * 32, k0 = blockIdx.y * 32;
  const int tx = threadIdx.x, ty = threadIdx.y;  // 32 x 8
#pragma unroll
  for (int r = 0; r < 4; ++r)
    tile[ty + 8 * r][tx] = src[(size_t)(k0 + ty + 8 * r) * 512 + n0 + tx];
  __syncthreads();
#pragma unroll
  for (int r = 0; r < 4; ++r)
    dst[(size_t)(n0 + ty + 8 * r) * 512 + k0 + tx] =
        (unsigned short)f2b(scl * tile[tx][ty + 8 * r]);
}

// ---- fused weight transposes, K=1024 (4 jobs via blockIdx.z) ----
// z 0..1: sWf + z*524288 -> Wft0 + z*524288.  z 2..3: aWf + (z-2)*524288 -> aWft0 + ...
__global__ __launch_bounds__(256) void transpose_f_kernel(
    const float* __restrict__ sWf, const float* __restrict__ aWf,
    unsigned short* __restrict__ Wft0, unsigned short* __restrict__ aWft0) {
  const int z = blockIdx.z;
  const float* src = (z < 2 ? sWf + (size_t)z * 524288 : aWf + (size_t)(z - 2) * 524288);
  unsigned short* dst =
      (z < 2 ? Wft0 + (size_t)z * 524288 : aWft0 + (size_t)(z - 2) * 524288);
  __shared__ float tile[32][33];
  const int n0 = blockIdx.x * 32, k0 = blockIdx.y * 32;
  const int tx = threadIdx.x, ty = threadIdx.y;  // 32 x 8
#pragma unroll
  for (int r = 0; r < 4; ++r)
    tile[ty + 8 * r][tx] = src[(size_t)(k0 + ty + 8 * r) * 512 + n0 + tx];
  __syncthreads();
#pragma unroll
  for (int r = 0; r < 4; ++r)
    dst[(size_t)(n0 + ty + 8 * r) * 1024 + k0 + tx] =
        (unsigned short)f2b(tile[tx][ty + 8 * r]);
}

// ---- V f32 [4096][ld] (head cols at h*D) -> Vfr [bh][sc=32][dtile=D/16][lane][8] ----
__global__ __launch_bounds__(256) void vtrans_frag_kernel(
    const float* __restrict__ V, int ld, int nh, int D,
    unsigned short* __restrict__ Vfr) {
  __shared__ float tile[32][33];
  const int s0 = blockIdx.x * 32, d0 = blockIdx.y * 32;
  const int bh = blockIdx.z;
  const int b = bh / nh, h = bh % nh;
  const int tx = threadIdx.x, ty = threadIdx.y;  // 32 x 8
  const float* src = V + ((size_t)b * 1024 + s0) * ld + h * D + d0;
#pragma unroll
  for (int r = 0; r < 4; ++r)
    tile[ty + 8 * r][tx] = src[(size_t)(ty + 8 * r) * ld + tx];  // [s][d]
  __syncthreads();
  const int idx = ty * 32 + tx;
  if (idx < 128) {
    const int dj = idx & 31, sch = idx >> 5;  // d within tile, s-chunk of 8
    float v[8];
#pragma unroll
    for (int jj = 0; jj < 8; ++jj) v[jj] = tile[sch * 8 + jj][dj];
    const uint4 u = pack8(v);
    const int sc = s0 >> 5;
    const int dtile = (d0 + dj) >> 4;
    const int lane = sch * 16 + (dj & 15);
    *(uint4*)(Vfr + ((size_t)(bh * 32 + sc) * (D / 16) + dtile) * 512 + lane * 8) = u;
  }
}

// ---- cross-side encoder: rank-3 affine -> Kfr + Qbf (packed) + V f32 ----
// nh=2, D=256. Tables T*: rows 0..2 = vectors, row 3 (at +1536) = bias.
__global__ __launch_bounds__(256) void affine3_pack_kernel(
    const float* __restrict__ cx, const float* __restrict__ cy, int sel,
    const float* __restrict__ TK, const float* __restrict__ TV,
    const float* __restrict__ TQ, unsigned short* __restrict__ Kfr,
    unsigned short* __restrict__ Qbf, float* __restrict__ Vf) {
  const int row = blockIdx.x;
  const int b = row >> 10, s = row & 1023;
  const float x = cx[row];
  const float* y = cy + (size_t)row * 8 + 2 * sel;
  const float y0 = y[0], y1 = y[1];
  const int t = threadIdx.x;
  if (t < 128) {
    const bool isQ = t >= 64;
    const int c = t & 63;
    const int h = c >> 5;
    const int d0 = (c & 31) * 8;
    const float* T = isQ ? TQ : TK;
    float v[8];
#pragma unroll
    for (int j = 0; j < 8; ++j) {
      const int col = h * 256 + d0 + j;
      v[j] = x * T[col] + y0 * T[512 + col] + y1 * T[1024 + col] + T[1536 + col];
    }
    const uint4 u = pack8(v);
    const int bh = b * 2 + h;
    if (isQ) {
      *(uint4*)(Qbf + ((size_t)bh * 1024 + s) * 256 + d0) = u;
    } else {
      const int kc = d0 >> 5;
      const int lane = ((d0 & 31) >> 3) * 16 + (s & 15);
      *(uint4*)(Kfr + ((size_t)(bh * 8 + kc) * 64 + (s >> 4)) * 512 + lane * 8) = u;
    }
  } else {
    const int col0 = (t - 128) * 4;
    float4 o;
    float* op = (float*)&o;
#pragma unroll
    for (int j = 0; j < 4; ++j) {
      const int col = col0 + j;
      op[j] = x * TV[col] + y0 * TV[512 + col] + y1 * TV[1024 + col] + TV[1536 + col];
    }
    *(float4*)(Vf + (size_t)row * 512 + col0) = o;
  }
}

// ---- decoder rank-1 producers (nh=4, D=128): T rows [0]=w, [1]=bias ----
__global__ __launch_bounds__(64) void rank1_pack_kernel(
    const float* __restrict__ x, const float* __restrict__ T,
    unsigned short* __restrict__ dst, int isQ) {
  const int row = blockIdx.x;
  const int b = row >> 10, s = row & 1023;
  const float xv = x[row];
  const int c = threadIdx.x;        // 64 chunks of 8
  const int h = c >> 4;             // 16 chunks per head
  const int d0 = (c & 15) * 8;
  float v[8];
#pragma unroll
  for (int j = 0; j < 8; ++j) {
    const int col = h * 128 + d0 + j;
    v[j] = xv * T[col] + T[512 + col];
  }
  const uint4 u = pack8(v);
  const int bh = b * 4 + h;
  if (isQ) {
    *(uint4*)(dst + ((size_t)bh * 1024 + s) * 128 + d0) = u;
  } else {
    const int kc = d0 >> 5;
    const int lane = ((d0 & 31) >> 3) * 16 + (s & 15);
    *(uint4*)(dst + ((size_t)(bh * 4 + kc) * 64 + (s >> 4)) * 512 + lane * 8) = u;
  }
}

// ---- out[r,:] = cx[r]*W3[0,:] + y0*W3[1,:] + y1*W3[2,:] + bias (f32 + bf16) ----
__global__ __launch_bounds__(512) void affine3_kernel(
    const float* __restrict__ cx, const float* __restrict__ cy, int sel,
    const float* __restrict__ W3, const float* __restrict__ bias,
    float* __restrict__ out, unsigned short* __restrict__ outb) {
  const int r = blockIdx.x, j = threadIdx.x;
  const float* y = cy + (size_t)r * 8 + 2 * sel;
  const float v = cx[r] * W3[j] + y[0] * W3[512 + j] + y[1] * W3[1024 + j] + bias[j];
  if (out) out[(size_t)r * 512 + j] = v;
  if (outb) outb[(size_t)r * 512 + j] = (unsigned short)f2b(v);
}

// ---- out[r,:] = x[r]*w + b ----
__global__ __launch_bounds__(512) void rank1_kernel(
    const float* __restrict__ x, const float* __restrict__ w,
    const float* __restrict__ b, float* __restrict__ out,
    unsigned short* __restrict__ outb) {
  const int r = blockIdx.x, j = threadIdx.x;
  const float v = x[r] * w[j] + b[j];
  if (out) out[(size_t)r * 512 + j] = v;
  if (outb) outb[(size_t)r * 512 + j] = (unsigned short)f2b(v);
}

// ------------- split-K Wf GEMM (double-buffered): two K-halves via blockIdx.z ----
// kz=0: A = A0 (bf16 [4096][512]), writes C0, no bias.
// kz=1: A = F0+F1 (f32 pair, converted) if F0 else A1 (bf16); writes C1 + bias.
// Wt: [512][1024] bf16; kz selects column half.  ln sums C0+C1+res.
__global__ __launch_bounds__(256) void gemm_wf_kernel(
    const unsigned short* __restrict__ A0, const unsigned short* __restrict__ A1,
    const float* __restrict__ F0, const float* __restrict__ F1,
    const unsigned short* __restrict__ Wt, const float* __restrict__ bias,
    float* __restrict__ C0, float* __restrict__ C1) {
  constexpr int BM = 128, BN = 64, BK = 32, LDP = 40, K = 512, N = 512;
  __shared__ unsigned short As[2][BM * LDP];
  __shared__ unsigned short Bs[2][BN * LDP];
  const int kz = blockIdx.z;
  const int tid = threadIdx.x;
  const int lane = tid & 63, w = tid >> 6;
  const int bm = blockIdx.y * BM, bn = blockIdx.x * BN;
  const int wm = (w & 1) * 64, wn = (w >> 1) * 32;
  const int l15 = lane & 15, lq = lane >> 4;
  const int ar = tid >> 1, ac = (tid & 1) * 16;
  const int br = tid >> 2, bc = (tid & 3) * 8;
  const unsigned short* A = kz ? A1 : A0;
  const bool useF = (kz != 0) && (F0 != nullptr);
  const size_t arow = (size_t)(bm + ar) * 512;
  const size_t brow = (size_t)(bn + br) * 1024 + (size_t)kz * 512;
  f32x4 acc[4][2] = {};
  uint4 ra0, ra1, rb0;
#define GLOAD(k0_)                                                          \
  do {                                                                      \
    if (useF) {                                                             \
      const float* p0 = F0 + arow + (k0_) + ac;                             \
      const float* p1 = F1 + arow + (k0_) + ac;                             \
      float s[16];                                                          \
      const float4 x0 = *(const float4*)p0, x1 = *(const float4*)(p0 + 4);  \
      const float4 x2 = *(const float4*)(p0 + 8), x3 = *(const float4*)(p0 + 12); \
      const float4 y0 = *(const float4*)p1, y1 = *(const float4*)(p1 + 4);  \
      const float4 y2 = *(const float4*)(p1 + 8), y3 = *(const float4*)(p1 + 12); \
      s[0] = x0.x + y0.x; s[1] = x0.y + y0.y; s[2] = x0.z + y0.z; s[3] = x0.w + y0.w; \
      s[4] = x1.x + y1.x; s[5] = x1.y + y1.y; s[6] = x1.z + y1.z; s[7] = x1.w + y1.w; \
      s[8] = x2.x + y2.x; s[9] = x2.y + y2.y; s[10] = x2.z + y2.z; s[11] = x2.w + y2.w; \
      s[12] = x3.x + y3.x; s[13] = x3.y + y3.y; s[14] = x3.z + y3.z; s[15] = x3.w + y3.w; \
      ra0 = pack8(s); ra1 = pack8(s + 8);                                   \
    } else {                                                                \
      ra0 = *(const uint4*)(A + arow + (k0_) + ac);                         \
      ra1 = *(const uint4*)(A + arow + (k0_) + ac + 8);                     \
    }                                                                       \
    rb0 = *(const uint4*)(Wt + brow + (k0_) + bc);                          \
  } while (0)
  GLOAD(0);
  *(uint4*)(As[0] + ar * LDP + ac) = ra0;
  *(uint4*)(As[0] + ar * LDP + ac + 8) = ra1;
  *(uint4*)(Bs[0] + br * LDP + bc) = rb0;
  __syncthreads();
  int buf = 0;
  for (int k0 = 0; k0 < K; k0 += BK) {
    const bool more = (k0 + BK) < K;
    if (more) GLOAD(k0 + BK);
    bf16x8 af[4], bfr[2];
#pragma unroll
    for (int mt = 0; mt < 4; ++mt)
      af[mt] = *(const bf16x8*)(As[buf] + (wm + mt * 16 + l15) * LDP + lq * 8);
#pragma unroll
    for (int nt = 0; nt < 2; ++nt)
      bfr[nt] = *(const bf16x8*)(Bs[buf] + (wn + nt * 16 + l15) * LDP + lq * 8);
#pragma unroll
    for (int mt = 0; mt < 4; ++mt)
#pragma unroll
      for (int nt = 0; nt < 2; ++nt)
        acc[mt][nt] =
            __builtin_amdgcn_mfma_f32_16x16x32_bf16(af[mt], bfr[nt], acc[mt][nt], 0, 0, 0);
    if (more) {
      *(uint4*)(As[buf ^ 1] + ar * LDP + ac) = ra0;
      *(uint4*)(As[buf ^ 1] + ar * LDP + ac + 8) = ra1;
      *(uint4*)(Bs[buf ^ 1] + br * LDP + bc) = rb0;
    }
    __syncthreads();
    buf ^= 1;
  }
#undef GLOAD
  float* C = kz ? C1 : C0;
#pragma unroll
  for (int nt = 0; nt < 2; ++nt) {
    const int col = bn + wn + nt * 16 + l15;
    const float bv = (kz && bias) ? bias[col] : 0.f;
#pragma unroll
    for (int mt = 0; mt < 4; ++mt) {
#pragma unroll
      for (int r = 0; r < 4; ++r) {
        const int row = bm + wm + mt * 16 + lq * 4 + r;
        C[(size_t)row * N + col] = acc[mt][nt][r] + bv;
      }
    }
  }
}

// ------- MFMA GEMM with fused frag-pack epilogue (K=512, single A) ---------------
// MODE 0: N=1536 = K|V|Q sections, nh=2, D=256 -> Kfr, Vfr, Qbf
// MODE 1: N=512  = V only, nh=4, D=128 -> Vfr
// MODE 2: N=512  = Q only, nh=4, D=128 -> Qbf (weights pre-scaled)
template <int MODE>
__global__ __launch_bounds__(256) void gemm_pack_kernel(
    const unsigned short* __restrict__ A0, const unsigned short* __restrict__ Wt,
    unsigned short* __restrict__ Kfr, unsigned short* __restrict__ Vfr,
    unsigned short* __restrict__ Qbf) {
  constexpr int BM = 128, BN = 64, BK = 32, LDP = 40, K = 512;
  __shared__ unsigned short As[2][BM * LDP];
  __shared__ unsigned short Bs[2][BN * LDP];
  const int tid = threadIdx.x;
  const int lane = tid & 63, w = tid >> 6;
  const int bm = blockIdx.y * BM, bn = blockIdx.x * BN;
  const int wm = (w & 1) * 64, wn = (w >> 1) * 32;
  const int l15 = lane & 15, lq = lane >> 4;
  const int ar = tid >> 1, ac = (tid & 1) * 16;
  const int br = tid >> 2, bc = (tid & 3) * 8;
  f32x4 acc[4][2] = {};
  uint4 ra0 = *(const uint4*)(A0 + (size_t)(bm + ar) * K + ac);
  uint4 ra1 = *(const uint4*)(A0 + (size_t)(bm + ar) * K + ac + 8);
  uint4 rb0 = *(const uint4*)(Wt + (size_t)(bn + br) * K + bc);
  *(uint4*)(As[0] + ar * LDP + ac) = ra0;
  *(uint4*)(As[0] + ar * LDP + ac + 8) = ra1;
  *(uint4*)(Bs[0] + br * LDP + bc) = rb0;
  __syncthreads();
  int buf = 0;
  for (int k0 = 0; k0 < K; k0 += BK) {
    const bool more = (k0 + BK) < K;
    if (more) {
      ra0 = *(const uint4*)(A0 + (size_t)(bm + ar) * K + k0 + BK + ac);
      ra1 = *(const uint4*)(A0 + (size_t)(bm + ar) * K + k0 + BK + ac + 8);
      rb0 = *(const uint4*)(Wt + (size_t)(bn + br) * K + k0 + BK + bc);
    }
    bf16x8 af[4], bfr[2];
#pragma unroll
    for (int mt = 0; mt < 4; ++mt)
      af[mt] = *(const bf16x8*)(As[buf] + (wm + mt * 16 + l15) * LDP + lq * 8);
#pragma unroll
    for (int nt = 0; nt < 2; ++nt)
      bfr[nt] = *(const bf16x8*)(Bs[buf] + (wn + nt * 16 + l15) * LDP + lq * 8);
#pragma unroll
    for (int mt = 0; mt < 4; ++mt)
#pragma unroll
      for (int nt = 0; nt < 2; ++nt)
        acc[mt][nt] =
            __builtin_amdgcn_mfma_f32_16x16x32_bf16(af[mt], bfr[nt], acc[mt][nt], 0, 0, 0);
    if (more) {
      *(uint4*)(As[buf ^ 1] + ar * LDP + ac) = ra0;
      *(uint4*)(As[buf ^ 1] + ar * LDP + ac + 8) = ra1;
      *(uint4*)(Bs[buf ^ 1] + br * LDP + bc) = rb0;
    }
    __syncthreads();
    buf ^= 1;
  }
  // ---- fused pack epilogue (element mappings match pack_kq/vtrans/qpack) ----
  const int b = bm >> 10;                       // BM=128 divides 1024
  const int s0base = (bm & 1023) + wm + lq * 4;
#pragma unroll
  for (int nt = 0; nt < 2; ++nt) {
    const int col = bn + wn + nt * 16 + l15;
    int sec, h, d, nh2, Dv;
    if constexpr (MODE == 0) {
      sec = col >> 9; const int c = col & 511; h = c >> 8; d = c & 255; nh2 = 2; Dv = 256;
    } else if constexpr (MODE == 1) {
      sec = 1; h = col >> 7; d = col & 127; nh2 = 4; Dv = 128;
    } else {
      sec = 2; h = col >> 7; d = col & 127; nh2 = 4; Dv = 128;
    }
    const int bh = b * nh2 + h;
#pragma unroll
    for (int mt = 0; mt < 4; ++mt) {
      const int s0 = s0base + mt * 16;          // 4 consecutive s: s0..s0+3
      const float* a = (const float*)&acc[mt][nt];
      if (sec == 2) {                           // Q: [bh][s][Dv]
        unsigned short* q = Qbf + ((size_t)bh * 1024 + s0) * Dv + d;
#pragma unroll
        for (int r = 0; r < 4; ++r) q[(size_t)r * Dv] = (unsigned short)f2b(a[r]);
      } else if (sec == 0) {                    // K frag: B-operand layout
        unsigned short* kp = Kfr +
            ((size_t)(bh * 8 + (d >> 5)) * 64 + (s0 >> 4)) * 512 +
            ((d & 31) >> 3) * 128 + (d & 7);
#pragma unroll
        for (int r = 0; r < 4; ++r)
          kp[((s0 & 15) + r) * 8] = (unsigned short)f2b(a[r]);
      } else {                                  // V frag: B-operand layout
        unsigned short* vp = Vfr +
            ((size_t)(bh * 32 + (s0 >> 5)) * (Dv / 16) + (d >> 4)) * 512 +
            (((s0 >> 3) & 3) * 16 + (d & 15)) * 8 + (s0 & 7);
        uint2 u;
        u.x = f2b(a[0]) | (f2b(a[1]) << 16);
        u.y = f2b(a[2]) | (f2b(a[3]) << 16);
        *(uint2*)vp = u;
      }
    }
  }
}

// ---------------- MFMA flash attention, frag-packed inputs -----------------------
// Block = 16 q rows of one (b,head) vs ONE KV side; 4 waves own 256 keys each.
// Q pre-scaled.  No max-subtraction (LN-normalized inputs keep |score| small).
// NKV==2: grid = 2*512, side = blockIdx>>9; writes f32 partials to Rp.
// NKV==1: writes bf16 directly with post_scale.
template <int D, int NKV>
__global__ __launch_bounds__(256, 2) void attn_mfma_kernel(
    const unsigned short* __restrict__ Qa, const unsigned short* __restrict__ Qb,
    const unsigned short* __restrict__ KfrA, const unsigned short* __restrict__ KfrB,
    const unsigned short* __restrict__ VfrA, const unsigned short* __restrict__ VfrB,
    float post_scale, int nh, unsigned short* __restrict__ R,
    float* __restrict__ Rp) {
  constexpr int NQS = NKV;
  constexpr int QP = D + 8;
  constexpr int WP = 1024 + 8;
  constexpr int DT = D / 64;
  const int tid = threadIdx.x;
  const int lane = tid & 63, w = tid >> 6;
  const int l15 = lane & 15, lq = lane >> 4;
  const int nbh = 4 * nh;
  int bx = blockIdx.x;
  int side = 0;
  if constexpr (NKV == 2) { side = bx >> 9; bx &= 511; }
  const int bh = bx % nbh;                   // XCD-local (b,h)
  const int qb16 = (bx / nbh) * 16;
  const int b = bh / nh, head = bh % nh;
  const size_t rowb = (size_t)b * 1024;
  const int colo = head * D;

  __shared__ unsigned short qsh[NQS * 16 * QP];
  __shared__ unsigned short wsh[16 * WP];
  __shared__ float redA[4][16];
  __shared__ float redB[4][16];

  // ---- stage Q tiles ----
  for (int idx = tid; idx < NQS * 16 * (D / 8); idx += 256) {
    const int st = idx / (16 * (D / 8));
    const int rem = idx - st * 16 * (D / 8);
    const int r = rem / (D / 8), ch = rem - r * (D / 8);
    const unsigned short* Q = st ? Qb : Qa;
    const uint4 u = *(const uint4*)(Q + ((size_t)bh * 1024 + qb16 + r) * D + ch * 8);
    *(uint4*)(qsh + st * 16 * QP + r * QP + ch * 8) = u;
  }
  __syncthreads();

  const unsigned short* Kp = (side ? KfrB : KfrA) + (size_t)bh * ((size_t)D * 1024);
  const unsigned short* Vp = (side ? VfrB : VfrA) + (size_t)bh * ((size_t)D * 1024);

  // ---- QK^T ----
  f32x4 acc[NQS][16] = {};
#pragma unroll 1
  for (int kc = 0; kc < D / 32; ++kc) {
    bf16x8 kf[16];
#pragma unroll
    for (int st = 0; st < 16; ++st)
      kf[st] = *(const bf16x8*)(Kp + ((size_t)kc * 64 + w * 16 + st) * 512 + lane * 8);
    const bf16x8 qa = *(const bf16x8*)(qsh + l15 * QP + kc * 32 + lq * 8);
    __builtin_amdgcn_s_setprio(1);
#pragma unroll
    for (int st = 0; st < 16; ++st)
      acc[0][st] = __builtin_amdgcn_mfma_f32_16x16x32_bf16(qa, kf[st], acc[0][st], 0, 0, 0);
    __builtin_amdgcn_s_setprio(0);
    if constexpr (NQS == 2) {
      const bf16x8 qb2 = *(const bf16x8*)(qsh + 16 * QP + l15 * QP + kc * 32 + lq * 8);
      __builtin_amdgcn_s_setprio(1);
#pragma unroll
      for (int st = 0; st < 16; ++st)
        acc[1][st] =
            __builtin_amdgcn_mfma_f32_16x16x32_bf16(qb2, kf[st], acc[1][st], 0, 0, 0);
      __builtin_amdgcn_s_setprio(0);
    }
  }

  // ---- exp (no max shift) + row sum ----
  float psA[4] = {0.f, 0.f, 0.f, 0.f}, psB[4] = {0.f, 0.f, 0.f, 0.f};
#pragma unroll
  for (int st = 0; st < 16; ++st)
#pragma unroll
    for (int r = 0; r < 4; ++r) {
      acc[0][st][r] = __expf(acc[0][st][r]);
      psA[r] += acc[0][st][r];
      if constexpr (NQS == 2) {
        acc[1][st][r] = __expf(acc[1][st][r]);
        psB[r] += acc[1][st][r];
      }
    }
#pragma unroll
  for (int o = 1; o < 16; o <<= 1)
#pragma unroll
    for (int r = 0; r < 4; ++r) {
      psA[r] += __shfl_xor(psA[r], o);
      if constexpr (NQS == 2) psB[r] += __shfl_xor(psB[r], o);
    }
  if (l15 == 0) {
#pragma unroll
    for (int r = 0; r < 4; ++r) {
      redA[w][lq * 4 + r] = psA[r];
      if constexpr (NQS == 2) redB[w][lq * 4 + r] = psB[r];
    }
  }
  __syncthreads();
  float invA[4], invB[4];
#pragma unroll
  for (int r = 0; r < 4; ++r) {
    invA[r] = 1.f / (redA[0][lq * 4 + r] + redA[1][lq * 4 + r] +
                     redA[2][lq * 4 + r] + redA[3][lq * 4 + r]);
    if constexpr (NQS == 2)
      invB[r] = 1.f / (redB[0][lq * 4 + r] + redB[1][lq * 4 + r] +
                       redB[2][lq * 4 + r] + redB[3][lq * 4 + r]);
  }
  // ---- combined weight strip ----
#pragma unroll
  for (int st = 0; st < 16; ++st)
#pragma unroll
    for (int r = 0; r < 4; ++r) {
      float wv = acc[0][st][r] * invA[r];
      if constexpr (NQS == 2) wv += acc[1][st][r] * invB[r];
      wsh[(lq * 4 + r) * WP + w * 256 + st * 16 + l15] = (unsigned short)f2b(wv);
    }
  __syncthreads();

  // ---- PV ----
  f32x4 acc_o[DT] = {};
#pragma unroll 1
  for (int sc = 0; sc < 32; sc += 2) {
    bf16x8 pa[2], vb[2][DT];
#pragma unroll
    for (int u = 0; u < 2; ++u) {
      pa[u] = *(const bf16x8*)(wsh + l15 * WP + (sc + u) * 32 + lq * 8);
#pragma unroll
      for (int dt = 0; dt < DT; ++dt)
        vb[u][dt] = *(const bf16x8*)(
            Vp + ((size_t)(sc + u) * (D / 16) + w * DT + dt) * 512 + lane * 8);
    }
    __builtin_amdgcn_s_setprio(1);
#pragma unroll
    for (int u = 0; u < 2; ++u)
#pragma unroll
      for (int dt = 0; dt < DT; ++dt)
        acc_o[dt] =
            __builtin_amdgcn_mfma_f32_16x16x32_bf16(pa[u], vb[u][dt], acc_o[dt], 0, 0, 0);
    __builtin_amdgcn_s_setprio(0);
  }

  // ---- epilogue ----
  if constexpr (NKV == 2) {
    float* dst = Rp + (size_t)side * (4096 * 512) + (rowb + qb16) * 512 + colo;
#pragma unroll
    for (int dt = 0; dt < DT; ++dt)
#pragma unroll
      for (int r = 0; r < 4; ++r) {
        const int q = lq * 4 + r;
        const int d = w * (DT * 16) + dt * 16 + l15;
        dst[(size_t)q * 512 + d] = acc_o[dt][r];
      }
  } else {
#pragma unroll
    for (int dt = 0; dt < DT; ++dt)
#pragma unroll
      for (int r = 0; r < 4; ++r) {
        const int q = lq * 4 + r;
        const int d = w * (DT * 16) + dt * 16 + l15;
        R[(rowb + qb16 + q) * 512 + colo + d] =
            (unsigned short)f2b(acc_o[dt][r] * post_scale);
      }
  }
}

// ---- out = LayerNorm(G0 + G1 + res) * g + b  (f32 out + optional bf16 out) ----
__global__ __launch_bounds__(256) void ln_kernel(
    const float* __restrict__ G0, const float* __restrict__ G1,
    const float* __restrict__ res, const float* __restrict__ g,
    const float* __restrict__ b, float* __restrict__ out,
    unsigned short* __restrict__ outb) {
  __shared__ float sh[4];
  const int row = blockIdx.x, tid = threadIdx.x;
  const size_t off = (size_t)row * 512;
  const float x0 = G0[off + tid] + G1[off + tid] + res[off + tid];
  const float x1 = G0[off + tid + 256] + G1[off + tid + 256] + res[off + tid + 256];
  const float mean = block_sum1(x0 + x1, sh) * (1.0f / 512.0f);
  const float d0 = x0 - mean, d1 = x1 - mean;
  const float var = block_sum1(d0 * d0 + d1 * d1, sh) * (1.0f / 512.0f);
  const float inv = rsqrtf(var + 1e-5f);
  const float y0 = d0 * inv * g[tid] + b[tid];
  const float y1 = d1 * inv * g[tid + 256] + b[tid + 256];
  out[off + tid] = y0;
  out[off + tid + 256] = y1;
  if (outb) {
    outb[off + tid] = (unsigned short)f2b(y0);
    outb[off + tid + 256] = (unsigned short)f2b(y1);
  }
}

extern "C" void kernel_launch(void* const* d_in, const int* in_sizes, int n_in,
                              void* d_out, int out_size, void* d_ws, size_t ws_size,
                              hipStream_t stream) {
  typedef unsigned short ushort_t;
  const float* cx   = (const float*)d_in[0];
  const float* cy   = (const float*)d_in[1];
  const float* txp  = (const float*)d_in[2];
  const float* in_W = (const float*)d_in[3];
  const float* in_b = (const float*)d_in[4];
  const float* cx_W = (const float*)d_in[5];
  const float* cx_b = (const float*)d_in[6];
  const float* tx_W = (const float*)d_in[7];
  const float* tx_b = (const float*)d_in[8];
  const float* sWk  = (const float*)d_in[9];
  const float* sWv  = (const float*)d_in[10];
  const float* sWq  = (const float*)d_in[11];
  const float* sWf  = (const float*)d_in[12];
  const float* sbf  = (const float*)d_in[13];
  const float* sg   = (const float*)d_in[14];
  const float* sb   = (const float*)d_in[15];
  const float* aWk  = (const float*)d_in[16];
  const float* aWv  = (const float*)d_in[17];
  const float* aWq  = (const float*)d_in[18];
  const float* aWf  = (const float*)d_in[19];
  const float* abf  = (const float*)d_in[20];
  const float* ag   = (const float*)d_in[21];
  const float* ab   = (const float*)d_in[22];

  const size_t MB = 1024 * 1024;
  char* ws = (char*)d_ws;
  float*    E     = (float*)(ws + 0 * MB);       // 8 MB
  ushort_t* Ebf   = (ushort_t*)(ws + 8 * MB);    // 4 MB
  float*    QA    = (float*)(ws + 12 * MB);      // 8 MB
  ushort_t* QAbf  = (ushort_t*)(ws + 20 * MB);   // 4 MB
  ushort_t* Rbbf  = (ushort_t*)(ws + 24 * MB);   // 4 MB
  float*    Rp    = (float*)(ws + 28 * MB);      // 16 MB attn f32 partials (2 sides)
  float*    G0    = (float*)(ws + 44 * MB);      // 8 MB Wf partial kz=0
  ushort_t* KfrA  = (ushort_t*)(ws + 52 * MB);   // 4 MB
  ushort_t* VfrA  = (ushort_t*)(ws + 56 * MB);   // 4 MB
  ushort_t* QbfA  = (ushort_t*)(ws + 60 * MB);   // 4 MB
  ushort_t* KfrB  = (ushort_t*)(ws + 64 * MB);   // 4 MB
  ushort_t* VfrB  = (ushort_t*)(ws + 68 * MB);   // 4 MB
  ushort_t* QbfB  = (ushort_t*)(ws + 72 * MB);   // 4 MB
  float*    cVf   = (float*)(ws + 76 * MB);      // 8 MB cross V f32
  float*    G1    = (float*)(ws + 84 * MB);      // 8 MB Wf partial kz=1
  ushort_t* Wkvqt0 = (ushort_t*)(ws + 92 * MB);  // 2 x 1.5 MB
  ushort_t* Wkvqt[2] = {Wkvqt0, Wkvqt0 + 786432};
  ushort_t* Wft0   = (ushort_t*)(ws + 95 * MB);  // 2 x 1 MB
  ushort_t* Wft[2] = {Wft0, Wft0 + 524288};
  ushort_t* aWvt0  = (ushort_t*)(ws + 97 * MB);  // 2 x 0.5 MB
  ushort_t* aWvt[2] = {aWvt0, aWvt0 + 262144};
  ushort_t* aWqt1  = (ushort_t*)(ws + 98 * MB);  // 0.5 MB
  ushort_t* aWft0  = (ushort_t*)(ws + 99 * MB);  // 2 x 1 MB
  ushort_t* aWft[2] = {aWft0, aWft0 + 524288};
  float*    Ttab   = (float*)(ws + 101 * MB);

  float* T_sc[2][3];
  for (int i = 0; i < 2; ++i)
    for (int w = 0; w < 3; ++w) T_sc[i][w] = Ttab + (size_t)(i * 3 + w) * 2048;
  float* T_cak[2] = {Ttab + 12288, Ttab + 12288 + 1024};
  float* T_caq0 = Ttab + 14336;

  const dim3 tb(32, 8);

  // ---- prep: fused weight transposes + projection tables ----
  transpose_kvq_kernel<<<dim3(16, 16, 9), tb, 0, stream>>>(sWk, sWv, sWq, aWv, aWq,
                                                           Wkvqt0, aWvt0, aWqt1);
  transpose_f_kernel<<<dim3(16, 32, 4), tb, 0, stream>>>(sWf, aWf, Wft0, aWft0);
  tabproj9_kernel<<<dim3(512, 9), 256, 0, stream>>>(in_W, in_b, cx_W, cx_b, tx_W, tx_b,
                                                    sWk, sWv, sWq, aWk, aWq, Ttab);

  // ---- initial activations ----
  affine3_kernel<<<4096, 512, 0, stream>>>(cx, cy, 0, in_W, in_b, E, Ebf);
  rank1_kernel<<<4096, 512, 0, stream>>>(txp, tx_W, tx_b, QA, QAbf);

  // ---- 8 self/cross encoder layers ----
  for (int p = 0; p < 4; ++p) {
    for (int i = 0; i < 2; ++i) {
      gemm_pack_kernel<0><<<dim3(24, 32), 256, 0, stream>>>(Ebf, Wkvqt[i], KfrA, VfrA,
                                                            QbfA);
      const float* F0 = nullptr;
      const float* F1 = nullptr;
      if (p > 0) {
        affine3_pack_kernel<<<4096, 256, 0, stream>>>(cx, cy, p, T_sc[i][0], T_sc[i][1],
                                                      T_sc[i][2], KfrB, QbfB, cVf);
        vtrans_frag_kernel<<<dim3(32, 8, 8), tb, 0, stream>>>(cVf, 512, 2, 256, VfrB);
        attn_mfma_kernel<256, 2><<<1024, 256, 0, stream>>>(
            QbfA, QbfB, KfrA, KfrB, VfrA, VfrB, 1.0f, 2, nullptr, Rp);
        F0 = Rp; F1 = Rp + 4096 * 512;
      } else {
        // x2 is x: 4 identical sdpa terms -> 4 * sdpa(sQ,sK,sV)
        attn_mfma_kernel<256, 1><<<512, 256, 0, stream>>>(
            QbfA, QbfA, KfrA, KfrA, VfrA, VfrA, 4.0f, 2, Rbbf, nullptr);
      }
      gemm_wf_kernel<<<dim3(8, 32, 2), 256, 0, stream>>>(
          Ebf, Rbbf, F0, F1, Wft[i], sbf + (size_t)i * 512, G0, G1);
      ln_kernel<<<4096, 256, 0, stream>>>(G0, G1, E, sg + (size_t)i * 512,
                                          sb + (size_t)i * 512, E, Ebf);
    }
  }

  // ---- 2 cross-attention decoder layers (nh=4, D=128) ----
  for (int i = 0; i < 2; ++i) {
    rank1_pack_kernel<<<4096, 64, 0, stream>>>(cx, T_cak[i], KfrA, 0);
    gemm_pack_kernel<1><<<dim3(8, 32), 256, 0, stream>>>(Ebf, aWvt[i], nullptr, VfrA,
                                                         nullptr);
    if (i == 0) {
      rank1_pack_kernel<<<4096, 64, 0, stream>>>(txp, T_caq0, QbfB, 1);
    } else {
      gemm_pack_kernel<2><<<dim3(8, 32), 256, 0, stream>>>(QAbf, aWqt1, nullptr, nullptr,
                                                           QbfB);
    }
    attn_mfma_kernel<128, 1><<<1024, 256, 0, stream>>>(
        QbfB, QbfB, KfrA, KfrA, VfrA, VfrA, 1.0f, 4, Rbbf, nullptr);
    gemm_wf_kernel<<<dim3(8, 32, 2), 256, 0, stream>>>(
        QAbf, Rbbf, nullptr, nullptr, aWft[i], abf + (size_t)i * 512, G0, G1);
    ln_kernel<<<4096, 256, 0, stream>>>(G0, G1, QA, ag + (size_t)i * 512,
                                        ab + (size_t)i * 512,
                                        (i == 1) ? (float*)d_out : QA,
                                        (i == 1) ? nullptr : QAbf);
  }
  (void)in_sizes; (void)n_in; (void)out_size; (void)ws_size;
}